// Round 2
// baseline (1486.985 us; speedup 1.0000x reference)
//
#include <hip/hip_runtime.h>
#include <math.h>

// ---------------- problem constants ----------------
#define NBATCH 16
#define NLIG   32
#define NPOC   192
#define NNODE  224                 // nodes per graph
#define TOTN   (NBATCH*NNODE)      // 3584
#define HD     128
#define NLAYER 4
#define NRBF   16
#define RADP   17                  // padded stride for rad[] (bank-conflict-free writes)
#define TDIMC  64
#define EBI2   (NBATCH*NLIG*NPOC)  // 98304 type-2 edges (poc->lig)
#define NTILE  ((2*EBI2)/128)      // 1536 edge tiles per layer
#define NPB    8                   // nodes per block in project/update
#define GAMMA_C 14.0625f           // (15/4)^2
#define RSTEP   0.26666666666666666f // 4/15
#define TWOPI   6.283185307179586f

__device__ __forceinline__ float silu_f(float x) { return x / (1.0f + __expf(-x)); }

// ---------------- K1: time embedding MLP  te[B][H] ----------------
__global__ void k_time(const float* __restrict__ t,
                       const float* __restrict__ w1, const float* __restrict__ b1,
                       const float* __restrict__ w2, const float* __restrict__ b2,
                       float* __restrict__ te) {
  __shared__ float emb[TDIMC];
  __shared__ float mid[HD];
  const int b = blockIdx.x, j = threadIdx.x;
  if (j < TDIMC) {
    const int half = TDIMC / 2;               // 32
    const float tv = t[b];
    const int i = j & 31;
    const float f = __expf(-logf(10000.0f) / (float)(half - 1) * (float)i);
    const float a = tv * f;
    emb[j] = (j < half) ? sinf(a) : cosf(a);
  }
  __syncthreads();
  float acc = b1[j];
  for (int k = 0; k < TDIMC; ++k) acc += emb[k] * w1[k*HD + j];
  mid[j] = silu_f(acc);
  __syncthreads();
  float acc2 = b2[j];
  for (int k = 0; k < HD; ++k) acc2 += mid[k] * w2[k*HD + j];
  te[b*HD + j] = acc2;
}

// ---------------- K2: node init + LN ----------------
__global__ void k_init(const float* __restrict__ ligc, const float* __restrict__ pocc,
                       const float* __restrict__ w_in, const float* __restrict__ b_in,
                       const float* __restrict__ nemb, const float* __restrict__ te,
                       const float* __restrict__ lng, const float* __restrict__ lnb,
                       float* __restrict__ h) {
  const int n = blockIdx.x, j = threadIdx.x;
  const int g = n / NNODE, loc = n - g*NNODE;
  const bool isl = loc < NLIG;
  float cx, cy, ang;
  if (isl) { cx = ligc[(g*NLIG + loc)*2]; cy = ligc[(g*NLIG + loc)*2 + 1];
             ang = TWOPI * (float)loc / 32.0f; }
  else { const int lp = loc - NLIG;
         cx = pocc[(g*NPOC + lp)*2]; cy = pocc[(g*NPOC + lp)*2 + 1];
         ang = TWOPI * (float)lp / 192.0f; }
  const float sa = sinf(ang), ca = cosf(ang);
  const int ty = isl ? 1 : 0;
  const float v = b_in[j] + cx*w_in[j] + cy*w_in[HD + j] + sa*w_in[2*HD + j]
                + ca*w_in[3*HD + j] + nemb[ty*HD + j] + te[g*HD + j];
  __shared__ float sm[2], sq[2];
  float s = v, q = v*v;
  #pragma unroll
  for (int o = 32; o > 0; o >>= 1) { s += __shfl_down(s, o); q += __shfl_down(q, o); }
  if ((j & 63) == 0) { sm[j >> 6] = s; sq[j >> 6] = q; }
  __syncthreads();
  const float mean = (sm[0] + sm[1]) * (1.0f/HD);
  const float var  = (sq[0] + sq[1]) * (1.0f/HD) - mean*mean;
  h[n*HD + j] = (v - mean) * rsqrtf(var + 1e-5f) * lng[j] + lnb[j];
}

// ---------------- K3: per-layer projections hs = h@W1s, hd = h@W1d; zero agg; ebias ----------------
__global__ void k_project(const float* __restrict__ h, const float* __restrict__ mw1,
                          const float* __restrict__ mb1, const float* __restrict__ eemb,
                          float* __restrict__ hs, float* __restrict__ hd,
                          float* __restrict__ agg, float* __restrict__ eb, int l) {
  const int j = threadIdx.x;
  const float* W1 = mw1 + (size_t)l * 401 * HD;
  if (blockIdx.x == TOTN / NPB) {            // ebias block: eb[et] = ef@W1_ef + b1
    for (int et = 0; et < 4; ++et) {
      const float* ef = eemb + ((size_t)l * 4 + et) * HD;
      float acc = mb1[l*HD + j];
      for (int k = 0; k < HD; ++k) acc += ef[k] * W1[(256 + k)*HD + j];
      eb[et*HD + j] = acc;
    }
    return;
  }
  __shared__ float hr[NPB][HD];
  const int n0 = blockIdx.x * NPB;
  #pragma unroll
  for (int nn = 0; nn < NPB; ++nn) hr[nn][j] = h[(n0 + nn)*HD + j];
  __syncthreads();
  float as[NPB], ad[NPB];
  #pragma unroll
  for (int nn = 0; nn < NPB; ++nn) { as[nn] = 0.f; ad[nn] = 0.f; }
  for (int k = 0; k < HD; ++k) {
    const float ws = W1[k*HD + j];
    const float wd = W1[(128 + k)*HD + j];
    #pragma unroll
    for (int nn = 0; nn < NPB; ++nn) { as[nn] += hr[nn][k]*ws; ad[nn] += hr[nn][k]*wd; }
  }
  #pragma unroll
  for (int nn = 0; nn < NPB; ++nn) {
    hs[(n0 + nn)*HD + j]  = as[nn];
    hd[(n0 + nn)*HD + j]  = ad[nn];
    agg[(n0 + nn)*HD + j] = 0.f;
  }
}

// ---------------- K5: bipartite edge messages (the big one) ----------------
// 128 edges per block, dst-run-ordered so each 8-edge group shares one dst.
// LDS: m_tile[128][132] + W2T[128][132] + geometry/weights (~151 KB).
__global__ __launch_bounds__(256, 1)
void k_edges(const float* __restrict__ ligc, const float* __restrict__ pocc,
             const float* __restrict__ hs, const float* __restrict__ hd,
             const float* __restrict__ mw1, const float* __restrict__ mb2,
             const float* __restrict__ mw2, const float* __restrict__ eb,
             float* __restrict__ agg, int l) {
  extern __shared__ float lds[];
  float* m_t  = lds;                  // [128][132]
  float* w2t  = m_t + 128*132;        // [128][132] (transposed W2: w2t[j][k])
  float* rad  = w2t + 128*132;        // [128][RADP]
  float* dis  = rad + 128*RADP;       // [128]
  int*   srcn = (int*)(dis + 128);    // [128]
  int*   dstn = srcn + 128;           // [128]
  float* wrbf = (float*)(dstn + 128); // [16][128]
  float* wdst = wrbf + 16*128;        // [128]
  float* ebl  = wdst + 128;           // [128]
  float* b2l  = ebl + 128;            // [128]

  const int tid = threadIdx.x;
  const int bid = blockIdx.x;
  const int et  = (bid < NTILE/2) ? 2 : 3;
  const float* W1 = mw1 + (size_t)l * 401 * HD;
  const float* W2 = mw2 + (size_t)l * HD * HD;

  // stage W2 transposed (coalesced global read, scattered LDS write)
  for (int idx = tid; idx < HD*HD; idx += 256) {
    const int k = idx >> 7, jj = idx & 127;
    w2t[jj*132 + k] = W2[idx];
  }
  for (int idx = tid; idx < NRBF*HD; idx += 256) wrbf[idx] = W1[384*HD + idx];

  if (tid < 128) {
    wdst[tid] = W1[400*HD + tid];
    ebl[tid]  = eb[et*HD + tid];
    b2l[tid]  = mb2[l*HD + tid];
    // per-edge setup: analytic src/dst/etype + geometry
    const int e = tid;
    int g, sl, dl;
    if (et == 2) {
      const int idx = bid*128 + e;
      g = idx / 6144; const int r0 = idx - g*6144;
      const int i = r0 / 192; const int p = r0 - i*192;
      sl = NLIG + p; dl = i;
    } else {
      const int idx = bid*128 + e - EBI2;
      g = idx / 6144; const int r0 = idx - g*6144;
      const int p = r0 >> 5; const int i = r0 & 31;
      sl = i; dl = NLIG + p;
    }
    srcn[e] = g*NNODE + sl;
    dstn[e] = g*NNODE + dl;
    float sx, sy, dx, dy;
    if (sl < NLIG) { sx = ligc[(g*NLIG + sl)*2]; sy = ligc[(g*NLIG + sl)*2 + 1]; }
    else { const int lp = sl - NLIG; sx = pocc[(g*NPOC + lp)*2]; sy = pocc[(g*NPOC + lp)*2 + 1]; }
    if (dl < NLIG) { dx = ligc[(g*NLIG + dl)*2]; dy = ligc[(g*NLIG + dl)*2 + 1]; }
    else { const int lp = dl - NLIG; dx = pocc[(g*NPOC + lp)*2]; dy = pocc[(g*NPOC + lp)*2 + 1]; }
    const float rx = sx - dx, ry = sy - dy;
    const float d = sqrtf(rx*rx + ry*ry);
    dis[e] = d;
    #pragma unroll
    for (int rr = 0; rr < NRBF; ++rr) {
      const float u = d - RSTEP * (float)rr;
      rad[e*RADP + rr] = __expf(-GAMMA_C * u * u);
    }
  }
  __syncthreads();

  // Phase B: pre-activation + silu -> m_tile (rows permuted: row(e) = (e&7)*16 + (e>>3))
  {
    const int j = tid & 127, eh = tid >> 7;
    for (int q0 = 0; q0 < 64; q0 += 8) {
      float hsv[8], hdv[8];
      #pragma unroll
      for (int u = 0; u < 8; ++u) {
        const int e = (eh << 6) + q0 + u;
        hsv[u] = hs[srcn[e]*HD + j];
        hdv[u] = hd[dstn[e]*HD + j];
      }
      #pragma unroll
      for (int u = 0; u < 8; ++u) {
        const int e = (eh << 6) + q0 + u;
        float pre = hsv[u] + hdv[u] + ebl[j] + dis[e]*wdst[j];
        #pragma unroll
        for (int rr = 0; rr < NRBF; ++rr) pre += rad[e*RADP + rr] * wrbf[rr*HD + j];
        const int row = ((e & 7) << 4) + (e >> 3);
        m_t[row*132 + j] = silu_f(pre);
      }
    }
  }
  __syncthreads();

  // Phase C: [128e x 128k] @ [128k x 128j], 8x8 register tiles, silu, per-dst reduce, atomic
  {
    const int jg = tid & 15, eg = tid >> 4;
    float acc[8][8];
    #pragma unroll
    for (int ii = 0; ii < 8; ++ii)
      #pragma unroll
      for (int jj = 0; jj < 8; ++jj) acc[ii][jj] = 0.f;
    for (int k0 = 0; k0 < HD; k0 += 4) {
      float4 wv[8], mv[8];
      #pragma unroll
      for (int x = 0; x < 8; ++x) wv[x] = *(const float4*)&w2t[(jg + 16*x)*132 + k0];
      #pragma unroll
      for (int x = 0; x < 8; ++x) mv[x] = *(const float4*)&m_t[(eg + 16*x)*132 + k0];
      #pragma unroll
      for (int ii = 0; ii < 8; ++ii)
        #pragma unroll
        for (int jj = 0; jj < 8; ++jj)
          acc[ii][jj] += mv[ii].x*wv[jj].x + mv[ii].y*wv[jj].y
                       + mv[ii].z*wv[jj].z + mv[ii].w*wv[jj].w;
    }
    const int dn = dstn[eg*8];          // 8 consecutive edges share dst (runs are 8-aligned)
    #pragma unroll
    for (int jj = 0; jj < 8; ++jj) {
      const int j = jg + 16*jj;
      const float bb = b2l[j];
      float s = 0.f;
      #pragma unroll
      for (int ii = 0; ii < 8; ++ii) s += silu_f(acc[ii][jj] + bb);
      atomicAdd(&agg[dn*HD + j], s);
    }
  }
}

// ---------------- K6: cycle edges + mean + update MLP + LN ----------------
__global__ void k_update(const float* __restrict__ ligc, const float* __restrict__ pocc,
                         const float* __restrict__ hs, const float* __restrict__ hd,
                         const float* __restrict__ mw1, const float* __restrict__ mb2,
                         const float* __restrict__ mw2, const float* __restrict__ eb,
                         const float* __restrict__ agg,
                         const float* __restrict__ uw1, const float* __restrict__ ub1,
                         const float* __restrict__ uw2, const float* __restrict__ ub2,
                         const float* __restrict__ lng, const float* __restrict__ lnb,
                         float* __restrict__ h, int l) {
  const int j = threadIdx.x;
  const int n0 = blockIdx.x * NPB;
  __shared__ float wrbf[NRBF*HD];
  __shared__ float wdst[HD], ebs[2*HD], b2s[HD];
  __shared__ float mA[NPB][HD], mB[NPB][HD], hr[NPB][HD], ar[NPB][HD], ur[NPB][HD];
  __shared__ float radS[NPB][2][NRBF];
  __shared__ float distS[NPB][2];
  __shared__ float sm[2][NPB], sq[2][NPB];
  const float* W1 = mw1 + (size_t)l * 401 * HD;
  const float* W2 = mw2 + (size_t)l * HD * HD;
  for (int idx = j; idx < NRBF*HD; idx += HD) wrbf[idx] = W1[384*HD + idx];
  wdst[j]     = W1[400*HD + j];
  ebs[j]      = eb[j];
  ebs[HD + j] = eb[HD + j];
  b2s[j]      = mb2[l*HD + j];
  { // geometry of the two cycle edges per node: thread (nn = j>>4, r = j&15)
    const int nn = j >> 4, rr = j & 15;
    const int n = n0 + nn;
    const int g = n / NNODE, loc = n - g*NNODE;
    const bool isl = loc < NLIG;
    float nx, ny;
    if (isl) { nx = ligc[(g*NLIG + loc)*2]; ny = ligc[(g*NLIG + loc)*2 + 1]; }
    else { const int lp = loc - NLIG; nx = pocc[(g*NPOC + lp)*2]; ny = pocc[(g*NPOC + lp)*2 + 1]; }
    #pragma unroll
    for (int ab = 0; ab < 2; ++ab) {
      int sl;
      if (isl) sl = (ab == 0) ? ((loc + NLIG - 1) & 31) : ((loc + 1) & 31);
      else { const int lp = loc - NLIG;
             const int sp = (ab == 0) ? (lp + NPOC - 1) % NPOC : (lp + 1) % NPOC;
             sl = NLIG + sp; }
      float sx, sy;
      if (sl < NLIG) { sx = ligc[(g*NLIG + sl)*2]; sy = ligc[(g*NLIG + sl)*2 + 1]; }
      else { const int lp = sl - NLIG; sx = pocc[(g*NPOC + lp)*2]; sy = pocc[(g*NPOC + lp)*2 + 1]; }
      const float rx = sx - nx, ry = sy - ny;
      const float d = sqrtf(rx*rx + ry*ry);
      const float u = d - RSTEP * (float)rr;
      radS[nn][ab][rr] = __expf(-GAMMA_C * u * u);
      if (rr == 0) distS[nn][ab] = d;
    }
  }
  __syncthreads();
  // Phase 1: cycle-edge pre + silu; stage h rows
  for (int nn = 0; nn < NPB; ++nn) {
    const int n = n0 + nn;
    const int g = n / NNODE, loc = n - g*NNODE;
    const bool isl = loc < NLIG;
    int slA, slB, etc_;
    if (isl) { slA = (loc + NLIG - 1) & 31; slB = (loc + 1) & 31; etc_ = 0; }
    else { const int lp = loc - NLIG;
           slA = NLIG + (lp + NPOC - 1) % NPOC; slB = NLIG + (lp + 1) % NPOC; etc_ = 1; }
    const int snA = g*NNODE + slA, snB = g*NNODE + slB;
    const float base = hd[n*HD + j] + ebs[etc_*HD + j];
    float pA = hs[snA*HD + j] + base + distS[nn][0]*wdst[j];
    float pB = hs[snB*HD + j] + base + distS[nn][1]*wdst[j];
    #pragma unroll
    for (int rr = 0; rr < NRBF; ++rr) {
      const float w = wrbf[rr*HD + j];
      pA += radS[nn][0][rr] * w;
      pB += radS[nn][1][rr] * w;
    }
    mA[nn][j] = silu_f(pA);
    mB[nn][j] = silu_f(pB);
    hr[nn][j] = h[n*HD + j];
  }
  __syncthreads();
  // Phase 2: batched W2 matvecs for cycle messages; finalize mean agg
  {
    float aA[NPB], aB[NPB];
    #pragma unroll
    for (int nn = 0; nn < NPB; ++nn) { aA[nn] = 0.f; aB[nn] = 0.f; }
    for (int k = 0; k < HD; ++k) {
      const float w = W2[k*HD + j];
      #pragma unroll
      for (int nn = 0; nn < NPB; ++nn) { aA[nn] += mA[nn][k]*w; aB[nn] += mB[nn][k]*w; }
    }
    #pragma unroll
    for (int nn = 0; nn < NPB; ++nn) {
      const int n = n0 + nn;
      const int loc = n % NNODE;
      const float inv_deg = (loc < NLIG) ? (1.0f/194.0f) : (1.0f/34.0f);
      const float cyc = silu_f(aA[nn] + b2s[j]) + silu_f(aB[nn] + b2s[j]);
      ar[nn][j] = (agg[n*HD + j] + cyc) * inv_deg;
    }
  }
  __syncthreads();
  // Phase 3: u1 = silu([h, agg] @ uw1 + b1)
  {
    float aU[NPB];
    #pragma unroll
    for (int nn = 0; nn < NPB; ++nn) aU[nn] = 0.f;
    const float* U1 = uw1 + (size_t)l * 2 * HD * HD;
    for (int k = 0; k < HD; ++k) {
      const float w = U1[k*HD + j];
      #pragma unroll
      for (int nn = 0; nn < NPB; ++nn) aU[nn] += hr[nn][k]*w;
    }
    for (int k = 0; k < HD; ++k) {
      const float w = U1[(HD + k)*HD + j];
      #pragma unroll
      for (int nn = 0; nn < NPB; ++nn) aU[nn] += ar[nn][k]*w;
    }
    const float b1v = ub1[l*HD + j];
    #pragma unroll
    for (int nn = 0; nn < NPB; ++nn) ur[nn][j] = silu_f(aU[nn] + b1v);
  }
  __syncthreads();
  // Phase 4: u2 + residual + LN
  {
    float aV[NPB];
    #pragma unroll
    for (int nn = 0; nn < NPB; ++nn) aV[nn] = 0.f;
    const float* U2 = uw2 + (size_t)l * HD * HD;
    for (int k = 0; k < HD; ++k) {
      const float w = U2[k*HD + j];
      #pragma unroll
      for (int nn = 0; nn < NPB; ++nn) aV[nn] += ur[nn][k]*w;
    }
    const float b2v = ub2[l*HD + j];
    const float gv = lng[l*HD + j], bv = lnb[l*HD + j];
    float xs[NPB];
    #pragma unroll
    for (int nn = 0; nn < NPB; ++nn) {
      xs[nn] = hr[nn][j] + aV[nn] + b2v;
      float s = xs[nn], q = xs[nn]*xs[nn];
      #pragma unroll
      for (int o = 32; o > 0; o >>= 1) { s += __shfl_down(s, o); q += __shfl_down(q, o); }
      if ((j & 63) == 0) { sm[j >> 6][nn] = s; sq[j >> 6][nn] = q; }
    }
    __syncthreads();
    #pragma unroll
    for (int nn = 0; nn < NPB; ++nn) {
      const float mean = (sm[0][nn] + sm[1][nn]) * (1.0f/HD);
      const float var  = (sq[0][nn] + sq[1][nn]) * (1.0f/HD) - mean*mean;
      h[(n0 + nn)*HD + j] = (xs[nn] - mean) * rsqrtf(var + 1e-5f) * gv + bv;
    }
  }
}

// ---------------- K7: pool ligand nodes + head MLP ----------------
__global__ void k_head(const float* __restrict__ h, const float* __restrict__ hw1,
                       const float* __restrict__ hb1, const float* __restrict__ hw2,
                       const float* __restrict__ hb2, float* __restrict__ out) {
  const int b = blockIdx.x, j = threadIdx.x;
  __shared__ float pool[HD], mid[HD];
  __shared__ float sm[2];
  float s = 0.f;
  #pragma unroll
  for (int i = 0; i < NLIG; ++i) s += h[(b*NNODE + i)*HD + j];
  pool[j] = s * (1.0f/NLIG);
  __syncthreads();
  float acc = hb1[j];
  for (int k = 0; k < HD; ++k) acc += pool[k] * hw1[k*HD + j];
  mid[j] = silu_f(acc);
  __syncthreads();
  float v = mid[j] * hw2[j];
  #pragma unroll
  for (int o = 32; o > 0; o >>= 1) v += __shfl_down(v, o);
  if ((j & 63) == 0) sm[j >> 6] = v;
  __syncthreads();
  if (j == 0) out[b] = sm[0] + sm[1] + hb2[0];
}

// ---------------- launcher ----------------
extern "C" void kernel_launch(void* const* d_in, const int* in_sizes, int n_in,
                              void* d_out, int out_size, void* d_ws, size_t ws_size,
                              hipStream_t stream) {
  (void)in_sizes; (void)n_in; (void)out_size; (void)ws_size;
  const float* ligc = (const float*)d_in[0];
  const float* pocc = (const float*)d_in[1];
  const float* tarr = (const float*)d_in[2];
  const float* w_in = (const float*)d_in[3];
  const float* b_in = (const float*)d_in[4];
  const float* nemb = (const float*)d_in[5];
  const float* lnig = (const float*)d_in[6];
  const float* lnib = (const float*)d_in[7];
  const float* tw1  = (const float*)d_in[8];
  const float* tb1  = (const float*)d_in[9];
  const float* tw2  = (const float*)d_in[10];
  const float* tb2  = (const float*)d_in[11];
  const float* eemb = (const float*)d_in[12];
  const float* mw1  = (const float*)d_in[13];
  const float* mb1  = (const float*)d_in[14];
  const float* mw2  = (const float*)d_in[15];
  const float* mb2  = (const float*)d_in[16];
  const float* uw1  = (const float*)d_in[17];
  const float* ub1  = (const float*)d_in[18];
  const float* uw2  = (const float*)d_in[19];
  const float* ub2  = (const float*)d_in[20];
  const float* lng  = (const float*)d_in[21];
  const float* lnb  = (const float*)d_in[22];
  const float* hw1  = (const float*)d_in[23];
  const float* hb1  = (const float*)d_in[24];
  const float* hw2  = (const float*)d_in[25];
  const float* hb2  = (const float*)d_in[26];
  float* outp = (float*)d_out;

  float* ws  = (float*)d_ws;
  float* te  = ws;                 // [16][128]
  float* h   = te  + NBATCH*HD;    // [3584][128]
  float* hs  = h   + TOTN*HD;
  float* hd  = hs  + TOTN*HD;
  float* agg = hd  + TOTN*HD;
  float* eb  = agg + TOTN*HD;      // [4][128]

  const int SMEM_EDGES = (128*132*2 + 128*RADP + 128 + NRBF*128 + 3*128) * 4 + 2*128*4;
  hipFuncSetAttribute((const void*)k_edges, hipFuncAttributeMaxDynamicSharedMemorySize, SMEM_EDGES);

  k_time<<<NBATCH, HD, 0, stream>>>(tarr, tw1, tb1, tw2, tb2, te);
  k_init<<<TOTN, HD, 0, stream>>>(ligc, pocc, w_in, b_in, nemb, te, lnig, lnib, h);
  for (int l = 0; l < NLAYER; ++l) {
    k_project<<<TOTN/NPB + 1, HD, 0, stream>>>(h, mw1, mb1, eemb, hs, hd, agg, eb, l);
    k_edges<<<NTILE, 256, SMEM_EDGES, stream>>>(ligc, pocc, hs, hd, mw1, mb2, mw2, eb, agg, l);
    k_update<<<TOTN/NPB, HD, 0, stream>>>(ligc, pocc, hs, hd, mw1, mb2, mw2, eb, agg,
                                          uw1, ub1, uw2, ub2, lng, lnb, h, l);
  }
  k_head<<<NBATCH, HD, 0, stream>>>(h, hw1, hb1, hw2, hb2, outp);
}

// Round 3
// 784.836 us; speedup vs baseline: 1.8946x; 1.8946x over previous
//
#include <hip/hip_runtime.h>
#include <math.h>

// ---------------- problem constants ----------------
#define NBATCH 16
#define NLIG   32
#define NPOC   192
#define NNODE  224                 // nodes per graph
#define TOTN   (NBATCH*NNODE)      // 3584
#define HD     128
#define NLAYER 4
#define NRBF   16
#define TDIMC  64
#define EBI2   (NBATCH*NLIG*NPOC)  // 98304 type-2 edges (poc->lig)
#define NTILE  ((2*EBI2)/128)      // 1536 edge tiles per layer
#define NPB    8                   // nodes per block in project/update
#define GAMMA_C 14.0625f           // (15/4)^2
#define RSTEP   0.26666666666666666f // 4/15
#define TWOPI   6.283185307179586f
#define LDH    136                 // half stride for MFMA LDS tiles (16B-aligned rows)
#define RADW   20                  // float stride for rad[] (float4-aligned)

typedef _Float16 half_t;
typedef __attribute__((ext_vector_type(8))) _Float16 half8;
typedef __attribute__((ext_vector_type(4))) float f32x4;

__device__ __forceinline__ float silu_f(float x) { return x / (1.0f + __expf(-x)); }

// ---------------- K1: time embedding MLP  te[B][H] ----------------
__global__ void k_time(const float* __restrict__ t,
                       const float* __restrict__ w1, const float* __restrict__ b1,
                       const float* __restrict__ w2, const float* __restrict__ b2,
                       float* __restrict__ te) {
  __shared__ float emb[TDIMC];
  __shared__ float mid[HD];
  const int b = blockIdx.x, j = threadIdx.x;
  if (j < TDIMC) {
    const int half = TDIMC / 2;               // 32
    const float tv = t[b];
    const int i = j & 31;
    const float f = __expf(-logf(10000.0f) / (float)(half - 1) * (float)i);
    const float a = tv * f;
    emb[j] = (j < half) ? sinf(a) : cosf(a);
  }
  __syncthreads();
  float acc = b1[j];
  for (int k = 0; k < TDIMC; ++k) acc += emb[k] * w1[k*HD + j];
  mid[j] = silu_f(acc);
  __syncthreads();
  float acc2 = b2[j];
  for (int k = 0; k < HD; ++k) acc2 += mid[k] * w2[k*HD + j];
  te[b*HD + j] = acc2;
}

// ---------------- K2: node init + LN ----------------
__global__ void k_init(const float* __restrict__ ligc, const float* __restrict__ pocc,
                       const float* __restrict__ w_in, const float* __restrict__ b_in,
                       const float* __restrict__ nemb, const float* __restrict__ te,
                       const float* __restrict__ lng, const float* __restrict__ lnb,
                       float* __restrict__ h) {
  const int n = blockIdx.x, j = threadIdx.x;
  const int g = n / NNODE, loc = n - g*NNODE;
  const bool isl = loc < NLIG;
  float cx, cy, ang;
  if (isl) { cx = ligc[(g*NLIG + loc)*2]; cy = ligc[(g*NLIG + loc)*2 + 1];
             ang = TWOPI * (float)loc / 32.0f; }
  else { const int lp = loc - NLIG;
         cx = pocc[(g*NPOC + lp)*2]; cy = pocc[(g*NPOC + lp)*2 + 1];
         ang = TWOPI * (float)lp / 192.0f; }
  const float sa = sinf(ang), ca = cosf(ang);
  const int ty = isl ? 1 : 0;
  const float v = b_in[j] + cx*w_in[j] + cy*w_in[HD + j] + sa*w_in[2*HD + j]
                + ca*w_in[3*HD + j] + nemb[ty*HD + j] + te[g*HD + j];
  __shared__ float sm[2], sq[2];
  float s = v, q = v*v;
  #pragma unroll
  for (int o = 32; o > 0; o >>= 1) { s += __shfl_down(s, o); q += __shfl_down(q, o); }
  if ((j & 63) == 0) { sm[j >> 6] = s; sq[j >> 6] = q; }
  __syncthreads();
  const float mean = (sm[0] + sm[1]) * (1.0f/HD);
  const float var  = (sq[0] + sq[1]) * (1.0f/HD) - mean*mean;
  h[n*HD + j] = (v - mean) * rsqrtf(var + 1e-5f) * lng[j] + lnb[j];
}

// ---------------- K-W2CVT: per-layer W2 -> transposed f16 [j][k] ----------------
__global__ void k_w2cvt(const float* __restrict__ mw2, half_t* __restrict__ w2h) {
  __shared__ float ft[64][129];
  const int l = blockIdx.x >> 1, k0 = (blockIdx.x & 1) * 64;
  const float* W2 = mw2 + (size_t)l*HD*HD;
  const int t = threadIdx.x;
  for (int i = 0; i < 32; ++i) {
    const int idx = t + i*256;           // 8192 = 64k x 128j
    const int k = idx >> 7, j = idx & 127;
    ft[k][j] = W2[(k0 + k)*HD + j];
  }
  __syncthreads();
  half_t* out = w2h + (size_t)l*HD*HD;
  for (int i = 0; i < 32; ++i) {
    const int idx = t + i*256;           // 8192 = 128j x 64k
    const int j = idx >> 6, k = idx & 63;
    out[j*HD + k0 + k] = (half_t)ft[k][j];
  }
}

// ---------------- K3: per-layer projections hs = h@W1s, hd = h@W1d; zero agg; ebias ----------------
__global__ void k_project(const float* __restrict__ h, const float* __restrict__ mw1,
                          const float* __restrict__ mb1, const float* __restrict__ eemb,
                          float* __restrict__ hs, float* __restrict__ hd,
                          float* __restrict__ agg, float* __restrict__ eb, int l) {
  const int j = threadIdx.x;
  const float* W1 = mw1 + (size_t)l * 401 * HD;
  if (blockIdx.x == TOTN / NPB) {            // ebias block: eb[et] = ef@W1_ef + b1
    for (int et = 0; et < 4; ++et) {
      const float* ef = eemb + ((size_t)l * 4 + et) * HD;
      float acc = mb1[l*HD + j];
      for (int k = 0; k < HD; ++k) acc += ef[k] * W1[(256 + k)*HD + j];
      eb[et*HD + j] = acc;
    }
    return;
  }
  __shared__ float hr[NPB][HD];
  const int n0 = blockIdx.x * NPB;
  #pragma unroll
  for (int nn = 0; nn < NPB; ++nn) hr[nn][j] = h[(n0 + nn)*HD + j];
  __syncthreads();
  float as[NPB], ad[NPB];
  #pragma unroll
  for (int nn = 0; nn < NPB; ++nn) { as[nn] = 0.f; ad[nn] = 0.f; }
  for (int k = 0; k < HD; ++k) {
    const float ws = W1[k*HD + j];
    const float wd = W1[(128 + k)*HD + j];
    #pragma unroll
    for (int nn = 0; nn < NPB; ++nn) { as[nn] += hr[nn][k]*ws; ad[nn] += hr[nn][k]*wd; }
  }
  #pragma unroll
  for (int nn = 0; nn < NPB; ++nn) {
    hs[(n0 + nn)*HD + j]  = as[nn];
    hd[(n0 + nn)*HD + j]  = ad[nn];
    agg[(n0 + nn)*HD + j] = 0.f;
  }
}

// ---------------- K5: bipartite edge messages — MFMA version ----------------
// 128 edges/block, 256 threads (4 waves). LDS: m_t[128][LDH] f16 + w2t[128][LDH] f16
// + rad[128][RADW] f32 + srcn/dstn/b2l.  81408 B -> 2 blocks/CU.
__global__ __launch_bounds__(256, 2)
void k_edges(const float* __restrict__ ligc, const float* __restrict__ pocc,
             const float* __restrict__ hs, const float* __restrict__ hd,
             const float* __restrict__ mw1, const float* __restrict__ mb2,
             const half_t* __restrict__ w2h, const float* __restrict__ eb,
             float* __restrict__ agg, int l) {
  extern __shared__ char lds_raw[];
  half_t* m_t  = (half_t*)lds_raw;                 // [128][LDH]
  half_t* w2t  = m_t + 128*LDH;                    // [128][LDH]  (w2t[j][k] = W2[k][j])
  float*  rad  = (float*)(w2t + 128*LDH);          // [128][RADW] (r 0..15, dis at 16)
  int*    srcn = (int*)(rad + 128*RADW);           // [128]
  int*    dstn = srcn + 128;                       // [128]
  float*  b2l  = (float*)(dstn + 128);             // [128]

  const int tid = threadIdx.x;
  const int bid = blockIdx.x;
  const int et  = (bid < NTILE/2) ? 2 : 3;
  const float* W1 = mw1 + (size_t)l * 401 * HD;

  // stage w2t from pre-converted global [j][k] (stride HD) into LDS (stride LDH)
  {
    const half_t* W2H = w2h + (size_t)l*HD*HD;
    #pragma unroll
    for (int i = 0; i < 8; ++i) {
      const int idx16 = tid + i*256;               // 2048 chunks of 8 halfs
      const int j = idx16 >> 4, c = idx16 & 15;
      *(half8*)((char*)w2t + j*(LDH*2) + c*16) = *(const half8*)(W2H + (size_t)idx16*8);
    }
  }

  if (tid < 128) {
    b2l[tid] = mb2[l*HD + tid];
    // per-edge setup: analytic src/dst + geometry
    const int e = tid;
    int g, sl, dl;
    if (et == 2) {
      const int idx = bid*128 + e;
      g = idx / 6144; const int r0 = idx - g*6144;
      const int i = r0 / 192; const int p = r0 - i*192;
      sl = NLIG + p; dl = i;
    } else {
      const int idx = bid*128 + e - EBI2;
      g = idx / 6144; const int r0 = idx - g*6144;
      const int p = r0 >> 5; const int i = r0 & 31;
      sl = i; dl = NLIG + p;
    }
    srcn[e] = g*NNODE + sl;
    dstn[e] = g*NNODE + dl;
    float sx, sy, dx, dy;
    if (sl < NLIG) { sx = ligc[(g*NLIG + sl)*2]; sy = ligc[(g*NLIG + sl)*2 + 1]; }
    else { const int lp = sl - NLIG; sx = pocc[(g*NPOC + lp)*2]; sy = pocc[(g*NPOC + lp)*2 + 1]; }
    if (dl < NLIG) { dx = ligc[(g*NLIG + dl)*2]; dy = ligc[(g*NLIG + dl)*2 + 1]; }
    else { const int lp = dl - NLIG; dx = pocc[(g*NPOC + dl-NLIG)*2]; dy = pocc[(g*NPOC + dl-NLIG)*2 + 1]; }
    const float rx = sx - dx, ry = sy - dy;
    const float d = sqrtf(rx*rx + ry*ry);
    #pragma unroll
    for (int rr = 0; rr < NRBF; ++rr) {
      const float u = d - RSTEP * (float)rr;
      rad[e*RADW + rr] = __expf(-GAMMA_C * u * u);
    }
    rad[e*RADW + 16] = d;
  }
  __syncthreads();

  // Phase B: pre-activation + silu -> m_t[e][j] (f16)
  {
    const int j = tid & 127, eh = tid >> 7;
    float wr[16];
    #pragma unroll
    for (int r = 0; r < 16; ++r) wr[r] = W1[(384+r)*HD + j];
    const float wd  = W1[400*HD + j];
    const float ebv = eb[et*HD + j];
    const int e0 = eh*64;
    #pragma unroll 2
    for (int e = e0; e < e0+64; ++e) {
      const int sn = srcn[e], dn = dstn[e];
      const float hv = hs[sn*HD + j] + hd[dn*HD + j];
      const float4 r0 = *(const float4*)&rad[e*RADW];
      const float4 r1 = *(const float4*)&rad[e*RADW+4];
      const float4 r2 = *(const float4*)&rad[e*RADW+8];
      const float4 r3 = *(const float4*)&rad[e*RADW+12];
      const float dis = rad[e*RADW+16];
      float pre = hv + ebv + dis*wd;
      pre += r0.x*wr[0] + r0.y*wr[1] + r0.z*wr[2] + r0.w*wr[3];
      pre += r1.x*wr[4] + r1.y*wr[5] + r1.z*wr[6] + r1.w*wr[7];
      pre += r2.x*wr[8] + r2.y*wr[9] + r2.z*wr[10] + r2.w*wr[11];
      pre += r3.x*wr[12] + r3.y*wr[13] + r3.z*wr[14] + r3.w*wr[15];
      m_t[e*LDH + j] = (half_t)silu_f(pre);
    }
  }
  __syncthreads();

  // Phase C: MFMA [128e x 128k] @ [128k x 128j]; silu; 8-run reduce; atomic
  {
    const int wv = tid >> 6, lane = tid & 63;
    const int q = lane >> 4, c15 = lane & 15;
    const int ebase = wv*32;
    f32x4 acc[2][8];
    #pragma unroll
    for (int ii = 0; ii < 2; ++ii)
      #pragma unroll
      for (int jj = 0; jj < 8; ++jj) acc[ii][jj] = (f32x4){0.f,0.f,0.f,0.f};
    for (int k0 = 0; k0 < HD; k0 += 32) {
      half8 af[2], bf[8];
      #pragma unroll
      for (int ii = 0; ii < 2; ++ii)
        af[ii] = *(const half8*)&m_t[(ebase + ii*16 + c15)*LDH + k0 + 8*q];
      #pragma unroll
      for (int jj = 0; jj < 8; ++jj)
        bf[jj] = *(const half8*)&w2t[(jj*16 + c15)*LDH + k0 + 8*q];
      #pragma unroll
      for (int ii = 0; ii < 2; ++ii)
        #pragma unroll
        for (int jj = 0; jj < 8; ++jj)
          acc[ii][jj] = __builtin_amdgcn_mfma_f32_16x16x32_f16(af[ii], bf[jj], acc[ii][jj], 0, 0, 0);
    }
    #pragma unroll
    for (int ii = 0; ii < 2; ++ii) {
      const int dA = dstn[ebase + ii*16];
      const int dB = dstn[ebase + ii*16 + 8];
      #pragma unroll
      for (int jj = 0; jj < 8; ++jj) {
        const int col = jj*16 + c15;
        const float bb = b2l[col];
        float s = silu_f(acc[ii][jj][0] + bb) + silu_f(acc[ii][jj][1] + bb)
                + silu_f(acc[ii][jj][2] + bb) + silu_f(acc[ii][jj][3] + bb);
        s += __shfl_xor(s, 16);
        if (q == 0)      atomicAdd(&agg[dA*HD + col], s);
        else if (q == 2) atomicAdd(&agg[dB*HD + col], s);
      }
    }
  }
}

// ---------------- K6: cycle edges + mean + update MLP + LN ----------------
__global__ void k_update(const float* __restrict__ ligc, const float* __restrict__ pocc,
                         const float* __restrict__ hs, const float* __restrict__ hd,
                         const float* __restrict__ mw1, const float* __restrict__ mb2,
                         const float* __restrict__ mw2, const float* __restrict__ eb,
                         const float* __restrict__ agg,
                         const float* __restrict__ uw1, const float* __restrict__ ub1,
                         const float* __restrict__ uw2, const float* __restrict__ ub2,
                         const float* __restrict__ lng, const float* __restrict__ lnb,
                         float* __restrict__ h, int l) {
  const int j = threadIdx.x;
  const int n0 = blockIdx.x * NPB;
  __shared__ float wrbf[NRBF*HD];
  __shared__ float wdst[HD], ebs[2*HD], b2s[HD];
  __shared__ float mA[NPB][HD], mB[NPB][HD], hr[NPB][HD], ar[NPB][HD], ur[NPB][HD];
  __shared__ float radS[NPB][2][NRBF];
  __shared__ float distS[NPB][2];
  __shared__ float sm[2][NPB], sq[2][NPB];
  const float* W1 = mw1 + (size_t)l * 401 * HD;
  const float* W2 = mw2 + (size_t)l * HD * HD;
  for (int idx = j; idx < NRBF*HD; idx += HD) wrbf[idx] = W1[384*HD + idx];
  wdst[j]     = W1[400*HD + j];
  ebs[j]      = eb[j];
  ebs[HD + j] = eb[HD + j];
  b2s[j]      = mb2[l*HD + j];
  { // geometry of the two cycle edges per node: thread (nn = j>>4, r = j&15)
    const int nn = j >> 4, rr = j & 15;
    const int n = n0 + nn;
    const int g = n / NNODE, loc = n - g*NNODE;
    const bool isl = loc < NLIG;
    float nx, ny;
    if (isl) { nx = ligc[(g*NLIG + loc)*2]; ny = ligc[(g*NLIG + loc)*2 + 1]; }
    else { const int lp = loc - NLIG; nx = pocc[(g*NPOC + lp)*2]; ny = pocc[(g*NPOC + lp)*2 + 1]; }
    #pragma unroll
    for (int ab = 0; ab < 2; ++ab) {
      int sl;
      if (isl) sl = (ab == 0) ? ((loc + NLIG - 1) & 31) : ((loc + 1) & 31);
      else { const int lp = loc - NLIG;
             const int sp = (ab == 0) ? (lp + NPOC - 1) % NPOC : (lp + 1) % NPOC;
             sl = NLIG + sp; }
      float sx, sy;
      if (sl < NLIG) { sx = ligc[(g*NLIG + sl)*2]; sy = ligc[(g*NLIG + sl)*2 + 1]; }
      else { const int lp = sl - NLIG; sx = pocc[(g*NPOC + lp)*2]; sy = pocc[(g*NPOC + lp)*2 + 1]; }
      const float rx = sx - nx, ry = sy - ny;
      const float d = sqrtf(rx*rx + ry*ry);
      const float u = d - RSTEP * (float)rr;
      radS[nn][ab][rr] = __expf(-GAMMA_C * u * u);
      if (rr == 0) distS[nn][ab] = d;
    }
  }
  __syncthreads();
  // Phase 1: cycle-edge pre + silu; stage h rows
  for (int nn = 0; nn < NPB; ++nn) {
    const int n = n0 + nn;
    const int g = n / NNODE, loc = n - g*NNODE;
    const bool isl = loc < NLIG;
    int slA, slB, etc_;
    if (isl) { slA = (loc + NLIG - 1) & 31; slB = (loc + 1) & 31; etc_ = 0; }
    else { const int lp = loc - NLIG;
           slA = NLIG + (lp + NPOC - 1) % NPOC; slB = NLIG + (lp + 1) % NPOC; etc_ = 1; }
    const int snA = g*NNODE + slA, snB = g*NNODE + slB;
    const float base = hd[n*HD + j] + ebs[etc_*HD + j];
    float pA = hs[snA*HD + j] + base + distS[nn][0]*wdst[j];
    float pB = hs[snB*HD + j] + base + distS[nn][1]*wdst[j];
    #pragma unroll
    for (int rr = 0; rr < NRBF; ++rr) {
      const float w = wrbf[rr*HD + j];
      pA += radS[nn][0][rr] * w;
      pB += radS[nn][1][rr] * w;
    }
    mA[nn][j] = silu_f(pA);
    mB[nn][j] = silu_f(pB);
    hr[nn][j] = h[n*HD + j];
  }
  __syncthreads();
  // Phase 2: batched W2 matvecs for cycle messages; finalize mean agg
  {
    float aA[NPB], aB[NPB];
    #pragma unroll
    for (int nn = 0; nn < NPB; ++nn) { aA[nn] = 0.f; aB[nn] = 0.f; }
    for (int k = 0; k < HD; ++k) {
      const float w = W2[k*HD + j];
      #pragma unroll
      for (int nn = 0; nn < NPB; ++nn) { aA[nn] += mA[nn][k]*w; aB[nn] += mB[nn][k]*w; }
    }
    #pragma unroll
    for (int nn = 0; nn < NPB; ++nn) {
      const int n = n0 + nn;
      const int loc = n % NNODE;
      const float inv_deg = (loc < NLIG) ? (1.0f/194.0f) : (1.0f/34.0f);
      const float cyc = silu_f(aA[nn] + b2s[j]) + silu_f(aB[nn] + b2s[j]);
      ar[nn][j] = (agg[n*HD + j] + cyc) * inv_deg;
    }
  }
  __syncthreads();
  // Phase 3: u1 = silu([h, agg] @ uw1 + b1)
  {
    float aU[NPB];
    #pragma unroll
    for (int nn = 0; nn < NPB; ++nn) aU[nn] = 0.f;
    const float* U1 = uw1 + (size_t)l * 2 * HD * HD;
    for (int k = 0; k < HD; ++k) {
      const float w = U1[k*HD + j];
      #pragma unroll
      for (int nn = 0; nn < NPB; ++nn) aU[nn] += hr[nn][k]*w;
    }
    for (int k = 0; k < HD; ++k) {
      const float w = U1[(HD + k)*HD + j];
      #pragma unroll
      for (int nn = 0; nn < NPB; ++nn) aU[nn] += ar[nn][k]*w;
    }
    const float b1v = ub1[l*HD + j];
    #pragma unroll
    for (int nn = 0; nn < NPB; ++nn) ur[nn][j] = silu_f(aU[nn] + b1v);
  }
  __syncthreads();
  // Phase 4: u2 + residual + LN
  {
    float aV[NPB];
    #pragma unroll
    for (int nn = 0; nn < NPB; ++nn) aV[nn] = 0.f;
    const float* U2 = uw2 + (size_t)l * HD * HD;
    for (int k = 0; k < HD; ++k) {
      const float w = U2[k*HD + j];
      #pragma unroll
      for (int nn = 0; nn < NPB; ++nn) aV[nn] += ur[nn][k]*w;
    }
    const float b2v = ub2[l*HD + j];
    const float gv = lng[l*HD + j], bv = lnb[l*HD + j];
    float xs[NPB];
    #pragma unroll
    for (int nn = 0; nn < NPB; ++nn) {
      xs[nn] = hr[nn][j] + aV[nn] + b2v;
      float s = xs[nn], q = xs[nn]*xs[nn];
      #pragma unroll
      for (int o = 32; o > 0; o >>= 1) { s += __shfl_down(s, o); q += __shfl_down(q, o); }
      if ((j & 63) == 0) { sm[j >> 6][nn] = s; sq[j >> 6][nn] = q; }
    }
    __syncthreads();
    #pragma unroll
    for (int nn = 0; nn < NPB; ++nn) {
      const float mean = (sm[0][nn] + sm[1][nn]) * (1.0f/HD);
      const float var  = (sq[0][nn] + sq[1][nn]) * (1.0f/HD) - mean*mean;
      h[(n0 + nn)*HD + j] = (xs[nn] - mean) * rsqrtf(var + 1e-5f) * gv + bv;
    }
  }
}

// ---------------- K7: pool ligand nodes + head MLP ----------------
__global__ void k_head(const float* __restrict__ h, const float* __restrict__ hw1,
                       const float* __restrict__ hb1, const float* __restrict__ hw2,
                       const float* __restrict__ hb2, float* __restrict__ out) {
  const int b = blockIdx.x, j = threadIdx.x;
  __shared__ float pool[HD], mid[HD];
  __shared__ float sm[2];
  float s = 0.f;
  #pragma unroll
  for (int i = 0; i < NLIG; ++i) s += h[(b*NNODE + i)*HD + j];
  pool[j] = s * (1.0f/NLIG);
  __syncthreads();
  float acc = hb1[j];
  for (int k = 0; k < HD; ++k) acc += pool[k] * hw1[k*HD + j];
  mid[j] = silu_f(acc);
  __syncthreads();
  float v = mid[j] * hw2[j];
  #pragma unroll
  for (int o = 32; o > 0; o >>= 1) v += __shfl_down(v, o);
  if ((j & 63) == 0) sm[j >> 6] = v;
  __syncthreads();
  if (j == 0) out[b] = sm[0] + sm[1] + hb2[0];
}

// ---------------- launcher ----------------
extern "C" void kernel_launch(void* const* d_in, const int* in_sizes, int n_in,
                              void* d_out, int out_size, void* d_ws, size_t ws_size,
                              hipStream_t stream) {
  (void)in_sizes; (void)n_in; (void)out_size; (void)ws_size;
  const float* ligc = (const float*)d_in[0];
  const float* pocc = (const float*)d_in[1];
  const float* tarr = (const float*)d_in[2];
  const float* w_in = (const float*)d_in[3];
  const float* b_in = (const float*)d_in[4];
  const float* nemb = (const float*)d_in[5];
  const float* lnig = (const float*)d_in[6];
  const float* lnib = (const float*)d_in[7];
  const float* tw1  = (const float*)d_in[8];
  const float* tb1  = (const float*)d_in[9];
  const float* tw2  = (const float*)d_in[10];
  const float* tb2  = (const float*)d_in[11];
  const float* eemb = (const float*)d_in[12];
  const float* mw1  = (const float*)d_in[13];
  const float* mb1  = (const float*)d_in[14];
  const float* mw2  = (const float*)d_in[15];
  const float* mb2  = (const float*)d_in[16];
  const float* uw1  = (const float*)d_in[17];
  const float* ub1  = (const float*)d_in[18];
  const float* uw2  = (const float*)d_in[19];
  const float* ub2  = (const float*)d_in[20];
  const float* lng  = (const float*)d_in[21];
  const float* lnb  = (const float*)d_in[22];
  const float* hw1  = (const float*)d_in[23];
  const float* hb1  = (const float*)d_in[24];
  const float* hw2  = (const float*)d_in[25];
  const float* hb2  = (const float*)d_in[26];
  float* outp = (float*)d_out;

  float* ws  = (float*)d_ws;
  float* te  = ws;                 // [16][128]
  float* h   = te  + NBATCH*HD;    // [3584][128]
  float* hs  = h   + TOTN*HD;
  float* hd  = hs  + TOTN*HD;
  float* agg = hd  + TOTN*HD;
  float* eb  = agg + TOTN*HD;      // [4][128]
  half_t* w2h = (half_t*)(eb + 4*HD); // [L][128][128] f16 (transposed W2)

  const int SMEM_EDGES = 128*LDH*2*2 + 128*RADW*4 + 2*128*4 + 128*4;  // 81408
  hipFuncSetAttribute((const void*)k_edges, hipFuncAttributeMaxDynamicSharedMemorySize, SMEM_EDGES);

  k_time<<<NBATCH, HD, 0, stream>>>(tarr, tw1, tb1, tw2, tb2, te);
  k_init<<<TOTN, HD, 0, stream>>>(ligc, pocc, w_in, b_in, nemb, te, lnig, lnib, h);
  k_w2cvt<<<2*NLAYER, 256, 0, stream>>>(mw2, w2h);
  for (int l = 0; l < NLAYER; ++l) {
    k_project<<<TOTN/NPB + 1, HD, 0, stream>>>(h, mw1, mb1, eemb, hs, hd, agg, eb, l);
    k_edges<<<NTILE, 256, SMEM_EDGES, stream>>>(ligc, pocc, hs, hd, mw1, mb2, w2h, eb, agg, l);
    k_update<<<TOTN/NPB, HD, 0, stream>>>(ligc, pocc, hs, hd, mw1, mb2, mw2, eb, agg,
                                          uw1, ub1, uw2, ub2, lng, lnb, h, l);
  }
  k_head<<<NBATCH, HD, 0, stream>>>(h, hw1, hb1, hw2, hb2, outp);
}

// Round 7
// 559.824 us; speedup vs baseline: 2.6562x; 1.4019x over previous
//
#include <hip/hip_runtime.h>
#include <math.h>

// ---------------- problem constants ----------------
#define NBATCH 16
#define NLIG   32
#define NPOC   192
#define NNODE  224                 // nodes per graph
#define TOTN   (NBATCH*NNODE)      // 3584
#define HD     128
#define NLAYER 4
#define NRBF   16
#define TDIMC  64
#define EBI2   (NBATCH*NLIG*NPOC)  // 98304 type-2 edges (poc->lig)
#define NTILE  ((2*EBI2)/128)      // 1536 edge tiles per layer
#define NPBP   4                   // nodes per block in project
#define NPBU   4                   // nodes per block in update
#define GAMMA_C 14.0625f           // (15/4)^2
#define RSTEP   0.26666666666666666f // 4/15
#define TWOPI   6.283185307179586f
#define LDH    136                 // half stride for MFMA LDS m-tile (16B-aligned rows)
#define RADW   20                  // float stride for rad[] (float4-aligned; 16 rbf + dis + 3 zero pad)

typedef _Float16 half_t;
typedef __attribute__((ext_vector_type(8))) _Float16 half8;
typedef __attribute__((ext_vector_type(4))) float f32x4;

__device__ __forceinline__ float silu_f(float x) { return x / (1.0f + __expf(-x)); }

// ---------------- K1: time embedding MLP  te[B][H] ----------------
__global__ void k_time(const float* __restrict__ t,
                       const float* __restrict__ w1, const float* __restrict__ b1,
                       const float* __restrict__ w2, const float* __restrict__ b2,
                       float* __restrict__ te) {
  __shared__ float emb[TDIMC];
  __shared__ float mid[HD];
  const int b = blockIdx.x, j = threadIdx.x;
  if (j < TDIMC) {
    const int half = TDIMC / 2;               // 32
    const float tv = t[b];
    const int i = j & 31;
    const float f = __expf(-logf(10000.0f) / (float)(half - 1) * (float)i);
    const float a = tv * f;
    emb[j] = (j < half) ? sinf(a) : cosf(a);
  }
  __syncthreads();
  float acc = b1[j];
  for (int k = 0; k < TDIMC; ++k) acc += emb[k] * w1[k*HD + j];
  mid[j] = silu_f(acc);
  __syncthreads();
  float acc2 = b2[j];
  for (int k = 0; k < HD; ++k) acc2 += mid[k] * w2[k*HD + j];
  te[b*HD + j] = acc2;
}

// ---------------- K2: node init + LN ----------------
__global__ void k_init(const float* __restrict__ ligc, const float* __restrict__ pocc,
                       const float* __restrict__ w_in, const float* __restrict__ b_in,
                       const float* __restrict__ nemb, const float* __restrict__ te,
                       const float* __restrict__ lng, const float* __restrict__ lnb,
                       float* __restrict__ h) {
  const int n = blockIdx.x, j = threadIdx.x;
  const int g = n / NNODE, loc = n - g*NNODE;
  const bool isl = loc < NLIG;
  float cx, cy, ang;
  if (isl) { cx = ligc[(g*NLIG + loc)*2]; cy = ligc[(g*NLIG + loc)*2 + 1];
             ang = TWOPI * (float)loc / 32.0f; }
  else { const int lp = loc - NLIG;
         cx = pocc[(g*NPOC + lp)*2]; cy = pocc[(g*NPOC + lp)*2 + 1];
         ang = TWOPI * (float)lp / 192.0f; }
  const float sa = sinf(ang), ca = cosf(ang);
  const int ty = isl ? 1 : 0;
  const float v = b_in[j] + cx*w_in[j] + cy*w_in[HD + j] + sa*w_in[2*HD + j]
                + ca*w_in[3*HD + j] + nemb[ty*HD + j] + te[g*HD + j];
  __shared__ float sm[2], sq[2];
  float s = v, q = v*v;
  #pragma unroll
  for (int o = 32; o > 0; o >>= 1) { s += __shfl_down(s, o); q += __shfl_down(q, o); }
  if ((j & 63) == 0) { sm[j >> 6] = s; sq[j >> 6] = q; }
  __syncthreads();
  const float mean = (sm[0] + sm[1]) * (1.0f/HD);
  const float var  = (sq[0] + sq[1]) * (1.0f/HD) - mean*mean;
  h[n*HD + j] = (v - mean) * rsqrtf(var + 1e-5f) * lng[j] + lnb[j];
}

// ---------------- K-W2CVT: per-layer W2 -> transposed f16 [j][k] ----------------
__global__ void k_w2cvt(const float* __restrict__ mw2, half_t* __restrict__ w2h) {
  __shared__ float ft[64][129];
  const int l = blockIdx.x >> 1, k0 = (blockIdx.x & 1) * 64;
  const float* W2 = mw2 + (size_t)l*HD*HD;
  const int t = threadIdx.x;
  for (int i = 0; i < 32; ++i) {
    const int idx = t + i*256;           // 8192 = 64k x 128j
    const int k = idx >> 7, j = idx & 127;
    ft[k][j] = W2[(k0 + k)*HD + j];
  }
  __syncthreads();
  half_t* out = w2h + (size_t)l*HD*HD;
  for (int i = 0; i < 32; ++i) {
    const int idx = t + i*256;           // 8192 = 128j x 64k
    const int j = idx >> 6, k = idx & 63;
    out[j*HD + k0 + k] = (half_t)ft[k][j];
  }
}

// ---------------- K3: per-layer projections hs = h@W1s, hd = h@W1d; zero agg; ebias ----------------
__global__ void k_project(const float* __restrict__ h, const float* __restrict__ mw1,
                          const float* __restrict__ mb1, const float* __restrict__ eemb,
                          float* __restrict__ hs, float* __restrict__ hd,
                          float* __restrict__ agg, float* __restrict__ eb, int l) {
  const int j = threadIdx.x;
  const float* W1 = mw1 + (size_t)l * 401 * HD;
  if (blockIdx.x == TOTN / NPBP) {           // ebias block: eb[et] = ef@W1_ef + b1
    for (int et = 0; et < 4; ++et) {
      const float* ef = eemb + ((size_t)l * 4 + et) * HD;
      float acc = mb1[l*HD + j];
      for (int k = 0; k < HD; ++k) acc += ef[k] * W1[(256 + k)*HD + j];
      eb[et*HD + j] = acc;
    }
    return;
  }
  __shared__ float hr[NPBP][HD];
  const int n0 = blockIdx.x * NPBP;
  #pragma unroll
  for (int nn = 0; nn < NPBP; ++nn) hr[nn][j] = h[(n0 + nn)*HD + j];
  __syncthreads();
  float as[NPBP], ad[NPBP];
  #pragma unroll
  for (int nn = 0; nn < NPBP; ++nn) { as[nn] = 0.f; ad[nn] = 0.f; }
  for (int k = 0; k < HD; ++k) {
    const float ws = W1[k*HD + j];
    const float wd = W1[(128 + k)*HD + j];
    #pragma unroll
    for (int nn = 0; nn < NPBP; ++nn) { as[nn] += hr[nn][k]*ws; ad[nn] += hr[nn][k]*wd; }
  }
  #pragma unroll
  for (int nn = 0; nn < NPBP; ++nn) {
    hs[(n0 + nn)*HD + j]  = as[nn];
    hd[(n0 + nn)*HD + j]  = ad[nn];
    agg[(n0 + nn)*HD + j] = 0.f;
  }
}

// ---------------- K5: bipartite edge messages — MFMA + hoisted Phase B ----------------
// 128 edges/block, 256 threads (4 waves). LDS: m_t[128][LDH] f16 + rad[128][RADW] f32 + b2l.
// 45568 B -> 3 blocks/CU. B-fragments (W2^T f16) load straight from L2-resident w2h.
// Topology facts used (verified): every 64-edge thread-span has constant graph & dst;
// et=2: src walks 64 consecutive pocket rows; et=3: src cycles the 32 ligand rows (2 runs).
// Every 32-edge wave-span has a single dst.
__global__ __launch_bounds__(256, 3)
void k_edges(const float* __restrict__ ligc, const float* __restrict__ pocc,
             const float* __restrict__ hs, const float* __restrict__ hd,
             const float* __restrict__ mw1, const float* __restrict__ mb2,
             const half_t* __restrict__ w2h, const float* __restrict__ eb,
             float* __restrict__ agg, int l) {
  extern __shared__ char lds_raw[];
  half_t* m_t = (half_t*)lds_raw;                  // [128][LDH]
  float*  rad = (float*)(lds_raw + 128*LDH*2);     // [128][RADW]
  float*  b2l = rad + 128*RADW;                    // [128]

  const int tid = threadIdx.x;
  const int bid = blockIdx.x;
  const int et  = (bid < NTILE/2) ? 2 : 3;
  const float* W1 = mw1 + (size_t)l * 401 * HD;

  // Phase A: per-edge geometry -> rad[] (one thread per edge)
  if (tid < 128) {
    b2l[tid] = mb2[l*HD + tid];
    const int e = tid;
    int g, sl, dl;
    if (et == 2) {
      const int idx = bid*128 + e;
      g = idx / 6144; const int r0 = idx - g*6144;
      const int i = r0 / 192; const int p = r0 - i*192;
      sl = NLIG + p; dl = i;
    } else {
      const int idx = bid*128 + e - EBI2;
      g = idx / 6144; const int r0 = idx - g*6144;
      const int p = r0 >> 5; const int i = r0 & 31;
      sl = i; dl = NLIG + p;
    }
    float sx, sy, dx, dy;
    if (sl < NLIG) { sx = ligc[(g*NLIG + sl)*2]; sy = ligc[(g*NLIG + sl)*2 + 1]; }
    else { const int lp = sl - NLIG; sx = pocc[(g*NPOC + lp)*2]; sy = pocc[(g*NPOC + lp)*2 + 1]; }
    if (dl < NLIG) { dx = ligc[(g*NLIG + dl)*2]; dy = ligc[(g*NLIG + dl)*2 + 1]; }
    else { const int lp = dl - NLIG; dx = pocc[(g*NPOC + lp)*2]; dy = pocc[(g*NPOC + lp)*2 + 1]; }
    const float rx = sx - dx, ry = sy - dy;
    const float d = sqrtf(rx*rx + ry*ry);
    #pragma unroll
    for (int rr = 0; rr < NRBF; ++rr) {
      const float u = d - RSTEP * (float)rr;
      rad[e*RADW + rr] = __expf(-GAMMA_C * u * u);
    }
    rad[e*RADW + 16] = d;
    rad[e*RADW + 17] = 0.f; rad[e*RADW + 18] = 0.f; rad[e*RADW + 19] = 0.f;
  }
  __syncthreads();

  // Phase B: pre-activation + silu -> m_t[e][j] (f16), run-hoisted
  {
    const int j = tid & 127, eh = tid >> 7;
    const int e0 = eh * 64;
    float wr[20];
    #pragma unroll
    for (int r = 0; r < 16; ++r) wr[r] = W1[(384 + r)*HD + j];
    wr[16] = W1[400*HD + j];
    wr[17] = 0.f; wr[18] = 0.f; wr[19] = 0.f;
    const float ebv = eb[et*HD + j];

    if (et == 2) {
      const int idx0 = bid*128 + e0;
      const int g = idx0 / 6144; const int r0 = idx0 - g*6144;
      const int i = r0 / 192;    const int p0 = r0 - i*192;   // span stays in one 192-run
      const float hdc = hd[(size_t)(g*NNODE + i)*HD + j] + ebv;
      const float* hp = hs + (size_t)(g*NNODE + NLIG + p0)*HD + j;
      #pragma unroll 4
      for (int v = 0; v < 64; ++v) {
        const int e = e0 + v;
        const float hsv = hp[(size_t)v*HD];
        const f32x4 r0v = *(const f32x4*)&rad[e*RADW];
        const f32x4 r1v = *(const f32x4*)&rad[e*RADW + 4];
        const f32x4 r2v = *(const f32x4*)&rad[e*RADW + 8];
        const f32x4 r3v = *(const f32x4*)&rad[e*RADW + 12];
        const f32x4 r4v = *(const f32x4*)&rad[e*RADW + 16];
        float pre = hsv + hdc;
        pre += r0v.x*wr[0] + r0v.y*wr[1] + r0v.z*wr[2] + r0v.w*wr[3];
        pre += r1v.x*wr[4] + r1v.y*wr[5] + r1v.z*wr[6] + r1v.w*wr[7];
        pre += r2v.x*wr[8] + r2v.y*wr[9] + r2v.z*wr[10] + r2v.w*wr[11];
        pre += r3v.x*wr[12] + r3v.y*wr[13] + r3v.z*wr[14] + r3v.w*wr[15];
        pre += r4v.x*wr[16] + r4v.y*wr[17] + r4v.z*wr[18] + r4v.w*wr[19];
        m_t[e*LDH + j] = (half_t)silu_f(pre);
      }
    } else {
      const int idx0 = bid*128 + e0 - EBI2;
      const int g = idx0 / 6144; const int r0 = idx0 - g*6144;
      const int p0 = r0 >> 5;                                  // two runs: p0, p0+1
      const float* hsp = hs + (size_t)(g*NNODE)*HD + j;
      float hsr[32];
      #pragma unroll
      for (int ii = 0; ii < 32; ++ii) hsr[ii] = hsp[(size_t)ii*HD];
      #pragma unroll
      for (int hf = 0; hf < 2; ++hf) {
        const float hdc = hd[(size_t)(g*NNODE + NLIG + p0 + hf)*HD + j] + ebv;
        #pragma unroll 4
        for (int ii = 0; ii < 32; ++ii) {
          const int e = e0 + hf*32 + ii;
          const f32x4 r0v = *(const f32x4*)&rad[e*RADW];
          const f32x4 r1v = *(const f32x4*)&rad[e*RADW + 4];
          const f32x4 r2v = *(const f32x4*)&rad[e*RADW + 8];
          const f32x4 r3v = *(const f32x4*)&rad[e*RADW + 12];
          const f32x4 r4v = *(const f32x4*)&rad[e*RADW + 16];
          float pre = hsr[ii] + hdc;
          pre += r0v.x*wr[0] + r0v.y*wr[1] + r0v.z*wr[2] + r0v.w*wr[3];
          pre += r1v.x*wr[4] + r1v.y*wr[5] + r1v.z*wr[6] + r1v.w*wr[7];
          pre += r2v.x*wr[8] + r2v.y*wr[9] + r2v.z*wr[10] + r2v.w*wr[11];
          pre += r3v.x*wr[12] + r3v.y*wr[13] + r3v.z*wr[14] + r3v.w*wr[15];
          pre += r4v.x*wr[16] + r4v.y*wr[17] + r4v.z*wr[18] + r4v.w*wr[19];
          m_t[e*LDH + j] = (half_t)silu_f(pre);
        }
      }
    }
  }
  __syncthreads();

  // Phase C: MFMA [128e x 128k] @ [128k x 128j]; silu; full-wave reduce; one atomic set
  {
    const int wv = tid >> 6, lane = tid & 63;
    const int q = lane >> 4, c15 = lane & 15;
    const int ebase = wv*32;
    // analytic single dst for this wave's 32 edges
    int dst;
    if (et == 2) {
      const int idx = bid*128 + ebase;
      const int g = idx / 6144; const int r0 = idx - g*6144;
      dst = g*NNODE + r0/192;
    } else {
      const int idx = bid*128 + ebase - EBI2;
      const int g = idx / 6144; const int r0 = idx - g*6144;
      dst = g*NNODE + NLIG + (r0 >> 5);
    }
    const half_t* W2H = w2h + (size_t)l*HD*HD;
    f32x4 acc[2][8];
    #pragma unroll
    for (int ii = 0; ii < 2; ++ii)
      #pragma unroll
      for (int jj = 0; jj < 8; ++jj) acc[ii][jj] = (f32x4){0.f,0.f,0.f,0.f};
    for (int k0 = 0; k0 < HD; k0 += 32) {
      half8 af[2], bf[8];
      #pragma unroll
      for (int ii = 0; ii < 2; ++ii)
        af[ii] = *(const half8*)&m_t[(ebase + ii*16 + c15)*LDH + k0 + 8*q];
      #pragma unroll
      for (int jj = 0; jj < 8; ++jj)
        bf[jj] = *(const half8*)&W2H[(size_t)(jj*16 + c15)*HD + k0 + 8*q];
      #pragma unroll
      for (int ii = 0; ii < 2; ++ii)
        #pragma unroll
        for (int jj = 0; jj < 8; ++jj)
          acc[ii][jj] = __builtin_amdgcn_mfma_f32_16x16x32_f16(af[ii], bf[jj], acc[ii][jj], 0, 0, 0);
    }
    #pragma unroll
    for (int jj = 0; jj < 8; ++jj) {
      const int col = jj*16 + c15;
      const float bb = b2l[col];
      float s = 0.f;
      #pragma unroll
      for (int ii = 0; ii < 2; ++ii) {
        s += silu_f(acc[ii][jj][0] + bb) + silu_f(acc[ii][jj][1] + bb)
           + silu_f(acc[ii][jj][2] + bb) + silu_f(acc[ii][jj][3] + bb);
      }
      s += __shfl_xor(s, 16);
      s += __shfl_xor(s, 32);
      if (q == 0) atomicAdd(&agg[(size_t)dst*HD + col], s);
    }
  }
}

// ---------------- K6: cycle edges + mean + update MLP + LN ----------------
__global__ void k_update(const float* __restrict__ ligc, const float* __restrict__ pocc,
                         const float* __restrict__ hs, const float* __restrict__ hd,
                         const float* __restrict__ mw1, const float* __restrict__ mb2,
                         const float* __restrict__ mw2, const float* __restrict__ eb,
                         const float* __restrict__ agg,
                         const float* __restrict__ uw1, const float* __restrict__ ub1,
                         const float* __restrict__ uw2, const float* __restrict__ ub2,
                         const float* __restrict__ lng, const float* __restrict__ lnb,
                         float* __restrict__ h, int l) {
  const int j = threadIdx.x;
  const int n0 = blockIdx.x * NPBU;
  __shared__ float wrbf[NRBF*HD];
  __shared__ float wdst[HD], ebs[2*HD], b2s[HD];
  __shared__ float mA[NPBU][HD], mB[NPBU][HD], hr[NPBU][HD], ar[NPBU][HD], ur[NPBU][HD];
  __shared__ float radS[NPBU][2][NRBF];
  __shared__ float distS[NPBU][2];
  __shared__ float sm[2][NPBU], sq[2][NPBU];
  const float* W1 = mw1 + (size_t)l * 401 * HD;
  const float* W2 = mw2 + (size_t)l * HD * HD;
  for (int idx = j; idx < NRBF*HD; idx += HD) wrbf[idx] = W1[384*HD + idx];
  wdst[j]     = W1[400*HD + j];
  ebs[j]      = eb[j];
  ebs[HD + j] = eb[HD + j];
  b2s[j]      = mb2[l*HD + j];
  { // geometry of the two cycle edges per node: thread (nn = j>>5, rr = j&31), rr<16 active
    const int nn = j >> 5, rr = j & 31;
    if (rr < 16) {
      const int n = n0 + nn;
      const int g = n / NNODE, loc = n - g*NNODE;
      const bool isl = loc < NLIG;
      float nx, ny;
      if (isl) { nx = ligc[(g*NLIG + loc)*2]; ny = ligc[(g*NLIG + loc)*2 + 1]; }
      else { const int lp = loc - NLIG; nx = pocc[(g*NPOC + lp)*2]; ny = pocc[(g*NPOC + lp)*2 + 1]; }
      #pragma unroll
      for (int ab = 0; ab < 2; ++ab) {
        int sl;
        if (isl) sl = (ab == 0) ? ((loc + NLIG - 1) & 31) : ((loc + 1) & 31);
        else { const int lp = loc - NLIG;
               const int sp = (ab == 0) ? (lp + NPOC - 1) % NPOC : (lp + 1) % NPOC;
               sl = NLIG + sp; }
        float sx, sy;
        if (sl < NLIG) { sx = ligc[(g*NLIG + sl)*2]; sy = ligc[(g*NLIG + sl)*2 + 1]; }
        else { const int lp = sl - NLIG; sx = pocc[(g*NPOC + lp)*2]; sy = pocc[(g*NPOC + lp)*2 + 1]; }
        const float rx = sx - nx, ry = sy - ny;
        const float d = sqrtf(rx*rx + ry*ry);
        const float u = d - RSTEP * (float)rr;
        radS[nn][ab][rr] = __expf(-GAMMA_C * u * u);
        if (rr == 0) distS[nn][ab] = d;
      }
    }
  }
  __syncthreads();
  // Phase 1: cycle-edge pre + silu; stage h rows
  for (int nn = 0; nn < NPBU; ++nn) {
    const int n = n0 + nn;
    const int g = n / NNODE, loc = n - g*NNODE;
    const bool isl = loc < NLIG;
    int slA, slB, etc_;
    if (isl) { slA = (loc + NLIG - 1) & 31; slB = (loc + 1) & 31; etc_ = 0; }
    else { const int lp = loc - NLIG;
           slA = NLIG + (lp + NPOC - 1) % NPOC; slB = NLIG + (lp + 1) % NPOC; etc_ = 1; }
    const int snA = g*NNODE + slA, snB = g*NNODE + slB;
    const float base = hd[n*HD + j] + ebs[etc_*HD + j];
    float pA = hs[snA*HD + j] + base + distS[nn][0]*wdst[j];
    float pB = hs[snB*HD + j] + base + distS[nn][1]*wdst[j];
    #pragma unroll
    for (int rr = 0; rr < NRBF; ++rr) {
      const float w = wrbf[rr*HD + j];
      pA += radS[nn][0][rr] * w;
      pB += radS[nn][1][rr] * w;
    }
    mA[nn][j] = silu_f(pA);
    mB[nn][j] = silu_f(pB);
    hr[nn][j] = h[n*HD + j];
  }
  __syncthreads();
  // Phase 2: batched W2 matvecs for cycle messages; finalize mean agg
  {
    float aA[NPBU], aB[NPBU];
    #pragma unroll
    for (int nn = 0; nn < NPBU; ++nn) { aA[nn] = 0.f; aB[nn] = 0.f; }
    for (int k = 0; k < HD; ++k) {
      const float w = W2[k*HD + j];
      #pragma unroll
      for (int nn = 0; nn < NPBU; ++nn) { aA[nn] += mA[nn][k]*w; aB[nn] += mB[nn][k]*w; }
    }
    #pragma unroll
    for (int nn = 0; nn < NPBU; ++nn) {
      const int n = n0 + nn;
      const int loc = n % NNODE;
      const float inv_deg = (loc < NLIG) ? (1.0f/194.0f) : (1.0f/34.0f);
      const float cyc = silu_f(aA[nn] + b2s[j]) + silu_f(aB[nn] + b2s[j]);
      ar[nn][j] = (agg[n*HD + j] + cyc) * inv_deg;
    }
  }
  __syncthreads();
  // Phase 3: u1 = silu([h, agg] @ uw1 + b1)
  {
    float aU[NPBU];
    #pragma unroll
    for (int nn = 0; nn < NPBU; ++nn) aU[nn] = 0.f;
    const float* U1 = uw1 + (size_t)l * 2 * HD * HD;
    for (int k = 0; k < HD; ++k) {
      const float w = U1[k*HD + j];
      #pragma unroll
      for (int nn = 0; nn < NPBU; ++nn) aU[nn] += hr[nn][k]*w;
    }
    for (int k = 0; k < HD; ++k) {
      const float w = U1[(HD + k)*HD + j];
      #pragma unroll
      for (int nn = 0; nn < NPBU; ++nn) aU[nn] += ar[nn][k]*w;
    }
    const float b1v = ub1[l*HD + j];
    #pragma unroll
    for (int nn = 0; nn < NPBU; ++nn) ur[nn][j] = silu_f(aU[nn] + b1v);
  }
  __syncthreads();
  // Phase 4: u2 + residual + LN
  {
    float aV[NPBU];
    #pragma unroll
    for (int nn = 0; nn < NPBU; ++nn) aV[nn] = 0.f;
    const float* U2 = uw2 + (size_t)l * HD * HD;
    for (int k = 0; k < HD; ++k) {
      const float w = U2[k*HD + j];
      #pragma unroll
      for (int nn = 0; nn < NPBU; ++nn) aV[nn] += ur[nn][k]*w;
    }
    const float b2v = ub2[l*HD + j];
    const float gv = lng[l*HD + j], bv = lnb[l*HD + j];
    float xs[NPBU];
    #pragma unroll
    for (int nn = 0; nn < NPBU; ++nn) {
      xs[nn] = hr[nn][j] + aV[nn] + b2v;
      float s = xs[nn], q = xs[nn]*xs[nn];
      #pragma unroll
      for (int o = 32; o > 0; o >>= 1) { s += __shfl_down(s, o); q += __shfl_down(q, o); }
      if ((j & 63) == 0) { sm[j >> 6][nn] = s; sq[j >> 6][nn] = q; }
    }
    __syncthreads();
    #pragma unroll
    for (int nn = 0; nn < NPBU; ++nn) {
      const float mean = (sm[0][nn] + sm[1][nn]) * (1.0f/HD);
      const float var  = (sq[0][nn] + sq[1][nn]) * (1.0f/HD) - mean*mean;
      h[(n0 + nn)*HD + j] = (xs[nn] - mean) * rsqrtf(var + 1e-5f) * gv + bv;
    }
  }
}

// ---------------- K7: pool ligand nodes + head MLP ----------------
__global__ void k_head(const float* __restrict__ h, const float* __restrict__ hw1,
                       const float* __restrict__ hb1, const float* __restrict__ hw2,
                       const float* __restrict__ hb2, float* __restrict__ out) {
  const int b = blockIdx.x, j = threadIdx.x;
  __shared__ float pool[HD], mid[HD];
  __shared__ float sm[2];
  float s = 0.f;
  #pragma unroll
  for (int i = 0; i < NLIG; ++i) s += h[(b*NNODE + i)*HD + j];
  pool[j] = s * (1.0f/NLIG);
  __syncthreads();
  float acc = hb1[j];
  for (int k = 0; k < HD; ++k) acc += pool[k] * hw1[k*HD + j];
  mid[j] = silu_f(acc);
  __syncthreads();
  float v = mid[j] * hw2[j];
  #pragma unroll
  for (int o = 32; o > 0; o >>= 1) v += __shfl_down(v, o);
  if ((j & 63) == 0) sm[j >> 6] = v;
  __syncthreads();
  if (j == 0) out[b] = sm[0] + sm[1] + hb2[0];
}

// ---------------- launcher ----------------
extern "C" void kernel_launch(void* const* d_in, const int* in_sizes, int n_in,
                              void* d_out, int out_size, void* d_ws, size_t ws_size,
                              hipStream_t stream) {
  (void)in_sizes; (void)n_in; (void)out_size; (void)ws_size;
  const float* ligc = (const float*)d_in[0];
  const float* pocc = (const float*)d_in[1];
  const float* tarr = (const float*)d_in[2];
  const float* w_in = (const float*)d_in[3];
  const float* b_in = (const float*)d_in[4];
  const float* nemb = (const float*)d_in[5];
  const float* lnig = (const float*)d_in[6];
  const float* lnib = (const float*)d_in[7];
  const float* tw1  = (const float*)d_in[8];
  const float* tb1  = (const float*)d_in[9];
  const float* tw2  = (const float*)d_in[10];
  const float* tb2  = (const float*)d_in[11];
  const float* eemb = (const float*)d_in[12];
  const float* mw1  = (const float*)d_in[13];
  const float* mb1  = (const float*)d_in[14];
  const float* mw2  = (const float*)d_in[15];
  const float* mb2  = (const float*)d_in[16];
  const float* uw1  = (const float*)d_in[17];
  const float* ub1  = (const float*)d_in[18];
  const float* uw2  = (const float*)d_in[19];
  const float* ub2  = (const float*)d_in[20];
  const float* lng  = (const float*)d_in[21];
  const float* lnb  = (const float*)d_in[22];
  const float* hw1  = (const float*)d_in[23];
  const float* hb1  = (const float*)d_in[24];
  const float* hw2  = (const float*)d_in[25];
  const float* hb2  = (const float*)d_in[26];
  float* outp = (float*)d_out;

  float* ws  = (float*)d_ws;
  float* te  = ws;                 // [16][128]
  float* h   = te  + NBATCH*HD;    // [3584][128]
  float* hs  = h   + TOTN*HD;
  float* hd  = hs  + TOTN*HD;
  float* agg = hd  + TOTN*HD;
  float* eb  = agg + TOTN*HD;      // [4][128]
  half_t* w2h = (half_t*)(eb + 4*HD); // [L][128][128] f16 (transposed W2)

  const int SMEM_EDGES = 128*LDH*2 + 128*RADW*4 + 128*4;  // 45568
  hipFuncSetAttribute((const void*)k_edges, hipFuncAttributeMaxDynamicSharedMemorySize, SMEM_EDGES);

  k_time<<<NBATCH, HD, 0, stream>>>(tarr, tw1, tb1, tw2, tb2, te);
  k_init<<<TOTN, HD, 0, stream>>>(ligc, pocc, w_in, b_in, nemb, te, lnig, lnib, h);
  k_w2cvt<<<2*NLAYER, 256, 0, stream>>>(mw2, w2h);
  for (int l = 0; l < NLAYER; ++l) {
    k_project<<<TOTN/NPBP + 1, HD, 0, stream>>>(h, mw1, mb1, eemb, hs, hd, agg, eb, l);
    k_edges<<<NTILE, 256, SMEM_EDGES, stream>>>(ligc, pocc, hs, hd, mw1, mb2, w2h, eb, agg, l);
    k_update<<<TOTN/NPBU, HD, 0, stream>>>(ligc, pocc, hs, hd, mw1, mb2, mw2, eb, agg,
                                           uw1, ub1, uw2, ub2, lng, lnb, h, l);
  }
  k_head<<<NBATCH, HD, 0, stream>>>(h, hw1, hb1, hw2, hb2, outp);
}

// Round 8
// 508.155 us; speedup vs baseline: 2.9262x; 1.1017x over previous
//
#include <hip/hip_runtime.h>
#include <math.h>

// ---------------- problem constants ----------------
#define NBATCH 16
#define NLIG   32
#define NPOC   192
#define NNODE  224                 // nodes per graph
#define TOTN   (NBATCH*NNODE)      // 3584
#define HD     128
#define NLAYER 4
#define NRBF   16
#define TDIMC  64
#define EBI2   (NBATCH*NLIG*NPOC)  // 98304 type-2 edges (poc->lig)
#define NTILE  ((2*EBI2)/128)      // 1536 edge tiles per layer
#define NPBP   4                   // nodes per block in project
#define NPBU   4                   // nodes per block in update
#define GAMMA_C 14.0625f           // (15/4)^2
#define RSTEP   0.26666666666666666f // 4/15
#define TWOPI   6.283185307179586f
#define LDH    136                 // half stride for MFMA LDS m-tile (16B-aligned rows)
#define RADH   40                  // half stride for rad_h rows (16B-aligned, bank-spread)

typedef _Float16 half_t;
typedef __attribute__((ext_vector_type(8))) _Float16 half8;
typedef __attribute__((ext_vector_type(4))) _Float16 half4;
typedef __attribute__((ext_vector_type(4))) float f32x4;

__device__ __forceinline__ float silu_f(float x) { return x / (1.0f + __expf(-x)); }

// ---------------- K1: time embedding MLP  te[B][H] ----------------
__global__ void k_time(const float* __restrict__ t,
                       const float* __restrict__ w1, const float* __restrict__ b1,
                       const float* __restrict__ w2, const float* __restrict__ b2,
                       float* __restrict__ te) {
  __shared__ float emb[TDIMC];
  __shared__ float mid[HD];
  const int b = blockIdx.x, j = threadIdx.x;
  if (j < TDIMC) {
    const int half = TDIMC / 2;               // 32
    const float tv = t[b];
    const int i = j & 31;
    const float f = __expf(-logf(10000.0f) / (float)(half - 1) * (float)i);
    const float a = tv * f;
    emb[j] = (j < half) ? sinf(a) : cosf(a);
  }
  __syncthreads();
  float acc = b1[j];
  for (int k = 0; k < TDIMC; ++k) acc += emb[k] * w1[k*HD + j];
  mid[j] = silu_f(acc);
  __syncthreads();
  float acc2 = b2[j];
  for (int k = 0; k < HD; ++k) acc2 += mid[k] * w2[k*HD + j];
  te[b*HD + j] = acc2;
}

// ---------------- K2: node init + LN ----------------
__global__ void k_init(const float* __restrict__ ligc, const float* __restrict__ pocc,
                       const float* __restrict__ w_in, const float* __restrict__ b_in,
                       const float* __restrict__ nemb, const float* __restrict__ te,
                       const float* __restrict__ lng, const float* __restrict__ lnb,
                       float* __restrict__ h) {
  const int n = blockIdx.x, j = threadIdx.x;
  const int g = n / NNODE, loc = n - g*NNODE;
  const bool isl = loc < NLIG;
  float cx, cy, ang;
  if (isl) { cx = ligc[(g*NLIG + loc)*2]; cy = ligc[(g*NLIG + loc)*2 + 1];
             ang = TWOPI * (float)loc / 32.0f; }
  else { const int lp = loc - NLIG;
         cx = pocc[(g*NPOC + lp)*2]; cy = pocc[(g*NPOC + lp)*2 + 1];
         ang = TWOPI * (float)lp / 192.0f; }
  const float sa = sinf(ang), ca = cosf(ang);
  const int ty = isl ? 1 : 0;
  const float v = b_in[j] + cx*w_in[j] + cy*w_in[HD + j] + sa*w_in[2*HD + j]
                + ca*w_in[3*HD + j] + nemb[ty*HD + j] + te[g*HD + j];
  __shared__ float sm[2], sq[2];
  float s = v, q = v*v;
  #pragma unroll
  for (int o = 32; o > 0; o >>= 1) { s += __shfl_down(s, o); q += __shfl_down(q, o); }
  if ((j & 63) == 0) { sm[j >> 6] = s; sq[j >> 6] = q; }
  __syncthreads();
  const float mean = (sm[0] + sm[1]) * (1.0f/HD);
  const float var  = (sq[0] + sq[1]) * (1.0f/HD) - mean*mean;
  h[n*HD + j] = (v - mean) * rsqrtf(var + 1e-5f) * lng[j] + lnb[j];
}

// ---------------- K-W2CVT: W2 -> f16 [j][k]; Wrbf -> f16 [j][32k] ----------------
__global__ void k_w2cvt(const float* __restrict__ mw2, const float* __restrict__ mw1,
                        half_t* __restrict__ w2h, half_t* __restrict__ wrbfh) {
  if (blockIdx.x >= 8) {   // wrbfh block: layer l = bid-8; rows j, k: 0..15 rbf, 16 wdst, 17..31 zero
    const int l = blockIdx.x - 8;
    const float* W1 = mw1 + (size_t)l * 401 * HD;
    const int t = threadIdx.x;
    const int j = t & 127, k0 = (t >> 7) * 16;
    half_t* out = wrbfh + (size_t)l*HD*32 + (size_t)j*32 + k0;
    for (int k = k0; k < k0 + 16; ++k) {
      float v = 0.f;
      if (k < 16) v = W1[(384 + k)*HD + j];
      else if (k == 16) v = W1[400*HD + j];
      out[k - k0] = (half_t)v;
    }
    return;
  }
  __shared__ float ft[64][129];
  const int l = blockIdx.x >> 1, k0 = (blockIdx.x & 1) * 64;
  const float* W2 = mw2 + (size_t)l*HD*HD;
  const int t = threadIdx.x;
  for (int i = 0; i < 32; ++i) {
    const int idx = t + i*256;           // 8192 = 64k x 128j
    const int k = idx >> 7, j = idx & 127;
    ft[k][j] = W2[(k0 + k)*HD + j];
  }
  __syncthreads();
  half_t* out = w2h + (size_t)l*HD*HD;
  for (int i = 0; i < 32; ++i) {
    const int idx = t + i*256;           // 8192 = 128j x 64k
    const int j = idx >> 6, k = idx & 63;
    out[j*HD + k0 + k] = (half_t)ft[k][j];
  }
}

// ---------------- K3: per-layer projections hs = h@W1s, hd = h@W1d; zero agg; ebias ----------------
__global__ void k_project(const float* __restrict__ h, const float* __restrict__ mw1,
                          const float* __restrict__ mb1, const float* __restrict__ eemb,
                          float* __restrict__ hs, float* __restrict__ hd,
                          float* __restrict__ agg, float* __restrict__ eb, int l) {
  const int j = threadIdx.x;
  const float* W1 = mw1 + (size_t)l * 401 * HD;
  if (blockIdx.x == TOTN / NPBP) {           // ebias block: eb[et] = ef@W1_ef + b1
    for (int et = 0; et < 4; ++et) {
      const float* ef = eemb + ((size_t)l * 4 + et) * HD;
      float acc = mb1[l*HD + j];
      for (int k = 0; k < HD; ++k) acc += ef[k] * W1[(256 + k)*HD + j];
      eb[et*HD + j] = acc;
    }
    return;
  }
  __shared__ float hr[NPBP][HD];
  const int n0 = blockIdx.x * NPBP;
  #pragma unroll
  for (int nn = 0; nn < NPBP; ++nn) hr[nn][j] = h[(n0 + nn)*HD + j];
  __syncthreads();
  float as[NPBP], ad[NPBP];
  #pragma unroll
  for (int nn = 0; nn < NPBP; ++nn) { as[nn] = 0.f; ad[nn] = 0.f; }
  for (int k = 0; k < HD; ++k) {
    const float ws = W1[k*HD + j];
    const float wd = W1[(128 + k)*HD + j];
    #pragma unroll
    for (int nn = 0; nn < NPBP; ++nn) { as[nn] += hr[nn][k]*ws; ad[nn] += hr[nn][k]*wd; }
  }
  #pragma unroll
  for (int nn = 0; nn < NPBP; ++nn) {
    hs[(n0 + nn)*HD + j]  = as[nn];
    hd[(n0 + nn)*HD + j]  = ad[nn];
    agg[(n0 + nn)*HD + j] = 0.f;
  }
}

// ---------------- K5: bipartite edge messages — dual-MFMA ----------------
// Phase A: rad_h[e][32] f16 (16 rbf, dist, zeros). Phase B1: rbf-dot via MFMA
// (A=Wrbf rows=j, B=rad cols=e -> C col=e, row=j -> b64 stores into m_t).
// Phase B2: m_t += hs[src]+hd[dst]+eb, silu (coalesced thread-per-column).
// Phase C: W2 MFMA + reduce + one atomic per (dst,col). LDS 45.5KB -> 3 blocks/CU.
__global__ __launch_bounds__(256, 3)
void k_edges(const float* __restrict__ ligc, const float* __restrict__ pocc,
             const float* __restrict__ hs, const float* __restrict__ hd,
             const half_t* __restrict__ wrbfh, const float* __restrict__ mb2,
             const half_t* __restrict__ w2h, const float* __restrict__ eb,
             float* __restrict__ agg, int l) {
  extern __shared__ char lds_raw[];
  half_t* m_t   = (half_t*)lds_raw;                  // [128][LDH]
  half_t* rad_h = m_t + 128*LDH;                     // [128][RADH] (k 0..31 valid)
  float*  b2l   = (float*)(rad_h + 128*RADH);        // [128]

  const int tid = threadIdx.x;
  const int bid = blockIdx.x;
  const int et  = (bid < NTILE/2) ? 2 : 3;

  // Phase A: per-edge geometry -> rad_h[] (one thread per edge)
  if (tid < 128) {
    b2l[tid] = mb2[l*HD + tid];
    const int e = tid;
    int g, sl, dl;
    if (et == 2) {
      const int idx = bid*128 + e;
      g = idx / 6144; const int r0 = idx - g*6144;
      const int i = r0 / 192; const int p = r0 - i*192;
      sl = NLIG + p; dl = i;
    } else {
      const int idx = bid*128 + e - EBI2;
      g = idx / 6144; const int r0 = idx - g*6144;
      const int p = r0 >> 5; const int i = r0 & 31;
      sl = i; dl = NLIG + p;
    }
    float sx, sy, dx, dy;
    if (sl < NLIG) { sx = ligc[(g*NLIG + sl)*2]; sy = ligc[(g*NLIG + sl)*2 + 1]; }
    else { const int lp = sl - NLIG; sx = pocc[(g*NPOC + lp)*2]; sy = pocc[(g*NPOC + lp)*2 + 1]; }
    if (dl < NLIG) { dx = ligc[(g*NLIG + dl)*2]; dy = ligc[(g*NLIG + dl)*2 + 1]; }
    else { const int lp = dl - NLIG; dx = pocc[(g*NPOC + lp)*2]; dy = pocc[(g*NPOC + lp)*2 + 1]; }
    const float rx = sx - dx, ry = sy - dy;
    const float d = sqrtf(rx*rx + ry*ry);
    half_t* rp = rad_h + e*RADH;
    #pragma unroll
    for (int rr = 0; rr < NRBF; ++rr) {
      const float u = d - RSTEP * (float)rr;
      rp[rr] = (half_t)__expf(-GAMMA_C * u * u);
    }
    rp[16] = (half_t)d;
    #pragma unroll
    for (int k = 17; k < 32; ++k) rp[k] = (half_t)0.f;
  }
  __syncthreads();

  // Phase B1: rbf-dot via MFMA, swapped operands -> b64 stores into m_t
  {
    const int lane = tid & 63;
    const int q = lane >> 4, c15 = lane & 15;
    const int ebase = (tid >> 6) * 32;
    const half_t* WR = wrbfh + (size_t)l*HD*32;
    half8 af[8];
    #pragma unroll
    for (int jb = 0; jb < 8; ++jb)
      af[jb] = *(const half8*)&WR[(size_t)(jb*16 + c15)*32 + 8*q];
    #pragma unroll
    for (int eb2 = 0; eb2 < 2; ++eb2) {
      const half8 bf2 = *(const half8*)&rad_h[(ebase + eb2*16 + c15)*RADH + 8*q];
      const int e = ebase + eb2*16 + c15;
      #pragma unroll
      for (int jb = 0; jb < 8; ++jb) {
        f32x4 a2 = (f32x4){0.f, 0.f, 0.f, 0.f};
        a2 = __builtin_amdgcn_mfma_f32_16x16x32_f16(af[jb], bf2, a2, 0, 0, 0);
        half4 hv;
        hv[0] = (half_t)a2[0]; hv[1] = (half_t)a2[1];
        hv[2] = (half_t)a2[2]; hv[3] = (half_t)a2[3];
        *(half4*)&m_t[(size_t)e*LDH + jb*16 + q*4] = hv;
      }
    }
  }
  __syncthreads();

  // Phase B2: m_t += hs[src] + hd[dst] + eb; silu (run-hoisted, coalesced)
  {
    const int j = tid & 127, eh = tid >> 7;
    const int e0 = eh * 64;
    const float ebv = eb[et*HD + j];

    if (et == 2) {
      const int idx0 = bid*128 + e0;
      const int g = idx0 / 6144; const int r0 = idx0 - g*6144;
      const int i = r0 / 192;    const int p0 = r0 - i*192;   // span stays in one 192-run
      const int gn = g*NNODE;
      const float hdc = hd[(size_t)(gn + i)*HD + j] + ebv;
      const float* hp = hs + (size_t)(gn + NLIG + p0)*HD + j;
      #pragma unroll 8
      for (int v = 0; v < 64; ++v) {
        const int e = e0 + v;
        const float pre = (float)m_t[e*LDH + j] + hp[(size_t)v*HD] + hdc;
        m_t[e*LDH + j] = (half_t)silu_f(pre);
      }
    } else {
      const int idx0 = bid*128 + e0 - EBI2;
      const int g = idx0 / 6144; const int r0 = idx0 - g*6144;
      const int p0 = r0 >> 5;                                  // two runs: p0, p0+1
      const int gn = g*NNODE;
      const float* hsp = hs + (size_t)gn*HD + j;
      float hsr[32];
      #pragma unroll
      for (int ii = 0; ii < 32; ++ii) hsr[ii] = hsp[(size_t)ii*HD];
      #pragma unroll
      for (int hf = 0; hf < 2; ++hf) {
        const float hdc = hd[(size_t)(gn + NLIG + p0 + hf)*HD + j] + ebv;
        #pragma unroll 8
        for (int ii = 0; ii < 32; ++ii) {
          const int e = e0 + hf*32 + ii;
          const float pre = (float)m_t[e*LDH + j] + hsr[ii] + hdc;
          m_t[e*LDH + j] = (half_t)silu_f(pre);
        }
      }
    }
  }
  __syncthreads();

  // Phase C: MFMA [128e x 128k] @ [128k x 128j]; silu; full-wave reduce; one atomic set
  {
    const int wv = tid >> 6, lane = tid & 63;
    const int q = lane >> 4, c15 = lane & 15;
    const int ebase = wv*32;
    // analytic single dst for this wave's 32 edges
    int dst;
    if (et == 2) {
      const int idx = bid*128 + ebase;
      const int g = idx / 6144; const int r0 = idx - g*6144;
      dst = g*NNODE + r0/192;
    } else {
      const int idx = bid*128 + ebase - EBI2;
      const int g = idx / 6144; const int r0 = idx - g*6144;
      dst = g*NNODE + NLIG + (r0 >> 5);
    }
    const half_t* W2H = w2h + (size_t)l*HD*HD;
    f32x4 acc[2][8];
    #pragma unroll
    for (int ii = 0; ii < 2; ++ii)
      #pragma unroll
      for (int jj = 0; jj < 8; ++jj) acc[ii][jj] = (f32x4){0.f,0.f,0.f,0.f};
    for (int k0 = 0; k0 < HD; k0 += 32) {
      half8 af[2], bf[8];
      #pragma unroll
      for (int ii = 0; ii < 2; ++ii)
        af[ii] = *(const half8*)&m_t[(ebase + ii*16 + c15)*LDH + k0 + 8*q];
      #pragma unroll
      for (int jj = 0; jj < 8; ++jj)
        bf[jj] = *(const half8*)&W2H[(size_t)(jj*16 + c15)*HD + k0 + 8*q];
      #pragma unroll
      for (int ii = 0; ii < 2; ++ii)
        #pragma unroll
        for (int jj = 0; jj < 8; ++jj)
          acc[ii][jj] = __builtin_amdgcn_mfma_f32_16x16x32_f16(af[ii], bf[jj], acc[ii][jj], 0, 0, 0);
    }
    #pragma unroll
    for (int jj = 0; jj < 8; ++jj) {
      const int col = jj*16 + c15;
      const float bb = b2l[col];
      float s = 0.f;
      #pragma unroll
      for (int ii = 0; ii < 2; ++ii) {
        s += silu_f(acc[ii][jj][0] + bb) + silu_f(acc[ii][jj][1] + bb)
           + silu_f(acc[ii][jj][2] + bb) + silu_f(acc[ii][jj][3] + bb);
      }
      s += __shfl_xor(s, 16);
      s += __shfl_xor(s, 32);
      if (q == 0) atomicAdd(&agg[(size_t)dst*HD + col], s);
    }
  }
}

// ---------------- K6: cycle edges + mean + update MLP + LN ----------------
__global__ void k_update(const float* __restrict__ ligc, const float* __restrict__ pocc,
                         const float* __restrict__ hs, const float* __restrict__ hd,
                         const float* __restrict__ mw1, const float* __restrict__ mb2,
                         const float* __restrict__ mw2, const float* __restrict__ eb,
                         const float* __restrict__ agg,
                         const float* __restrict__ uw1, const float* __restrict__ ub1,
                         const float* __restrict__ uw2, const float* __restrict__ ub2,
                         const float* __restrict__ lng, const float* __restrict__ lnb,
                         float* __restrict__ h, int l) {
  const int j = threadIdx.x;
  const int n0 = blockIdx.x * NPBU;
  __shared__ float wrbf[NRBF*HD];
  __shared__ float wdst[HD], ebs[2*HD], b2s[HD];
  __shared__ float mA[NPBU][HD], mB[NPBU][HD], hr[NPBU][HD], ar[NPBU][HD], ur[NPBU][HD];
  __shared__ float radS[NPBU][2][NRBF];
  __shared__ float distS[NPBU][2];
  __shared__ float sm[2][NPBU], sq[2][NPBU];
  const float* W1 = mw1 + (size_t)l * 401 * HD;
  const float* W2 = mw2 + (size_t)l * HD * HD;
  for (int idx = j; idx < NRBF*HD; idx += HD) wrbf[idx] = W1[384*HD + idx];
  wdst[j]     = W1[400*HD + j];
  ebs[j]      = eb[j];
  ebs[HD + j] = eb[HD + j];
  b2s[j]      = mb2[l*HD + j];
  { // geometry of the two cycle edges per node: thread (nn = j>>5, rr = j&31), rr<16 active
    const int nn = j >> 5, rr = j & 31;
    if (rr < 16) {
      const int n = n0 + nn;
      const int g = n / NNODE, loc = n - g*NNODE;
      const bool isl = loc < NLIG;
      float nx, ny;
      if (isl) { nx = ligc[(g*NLIG + loc)*2]; ny = ligc[(g*NLIG + loc)*2 + 1]; }
      else { const int lp = loc - NLIG; nx = pocc[(g*NPOC + lp)*2]; ny = pocc[(g*NPOC + lp)*2 + 1]; }
      #pragma unroll
      for (int ab = 0; ab < 2; ++ab) {
        int sl;
        if (isl) sl = (ab == 0) ? ((loc + NLIG - 1) & 31) : ((loc + 1) & 31);
        else { const int lp = loc - NLIG;
               const int sp = (ab == 0) ? (lp + NPOC - 1) % NPOC : (lp + 1) % NPOC;
               sl = NLIG + sp; }
        float sx, sy;
        if (sl < NLIG) { sx = ligc[(g*NLIG + sl)*2]; sy = ligc[(g*NLIG + sl)*2 + 1]; }
        else { const int lp = sl - NLIG; sx = pocc[(g*NPOC + lp)*2]; sy = pocc[(g*NPOC + lp)*2 + 1]; }
        const float rx = sx - nx, ry = sy - ny;
        const float d = sqrtf(rx*rx + ry*ry);
        const float u = d - RSTEP * (float)rr;
        radS[nn][ab][rr] = __expf(-GAMMA_C * u * u);
        if (rr == 0) distS[nn][ab] = d;
      }
    }
  }
  __syncthreads();
  // Phase 1: cycle-edge pre + silu; stage h rows
  for (int nn = 0; nn < NPBU; ++nn) {
    const int n = n0 + nn;
    const int g = n / NNODE, loc = n - g*NNODE;
    const bool isl = loc < NLIG;
    int slA, slB, etc_;
    if (isl) { slA = (loc + NLIG - 1) & 31; slB = (loc + 1) & 31; etc_ = 0; }
    else { const int lp = loc - NLIG;
           slA = NLIG + (lp + NPOC - 1) % NPOC; slB = NLIG + (lp + 1) % NPOC; etc_ = 1; }
    const int snA = g*NNODE + slA, snB = g*NNODE + slB;
    const float base = hd[n*HD + j] + ebs[etc_*HD + j];
    float pA = hs[snA*HD + j] + base + distS[nn][0]*wdst[j];
    float pB = hs[snB*HD + j] + base + distS[nn][1]*wdst[j];
    #pragma unroll
    for (int rr = 0; rr < NRBF; ++rr) {
      const float w = wrbf[rr*HD + j];
      pA += radS[nn][0][rr] * w;
      pB += radS[nn][1][rr] * w;
    }
    mA[nn][j] = silu_f(pA);
    mB[nn][j] = silu_f(pB);
    hr[nn][j] = h[n*HD + j];
  }
  __syncthreads();
  // Phase 2: batched W2 matvecs for cycle messages; finalize mean agg
  {
    float aA[NPBU], aB[NPBU];
    #pragma unroll
    for (int nn = 0; nn < NPBU; ++nn) { aA[nn] = 0.f; aB[nn] = 0.f; }
    for (int k = 0; k < HD; ++k) {
      const float w = W2[k*HD + j];
      #pragma unroll
      for (int nn = 0; nn < NPBU; ++nn) { aA[nn] += mA[nn][k]*w; aB[nn] += mB[nn][k]*w; }
    }
    #pragma unroll
    for (int nn = 0; nn < NPBU; ++nn) {
      const int n = n0 + nn;
      const int loc = n % NNODE;
      const float inv_deg = (loc < NLIG) ? (1.0f/194.0f) : (1.0f/34.0f);
      const float cyc = silu_f(aA[nn] + b2s[j]) + silu_f(aB[nn] + b2s[j]);
      ar[nn][j] = (agg[n*HD + j] + cyc) * inv_deg;
    }
  }
  __syncthreads();
  // Phase 3: u1 = silu([h, agg] @ uw1 + b1)
  {
    float aU[NPBU];
    #pragma unroll
    for (int nn = 0; nn < NPBU; ++nn) aU[nn] = 0.f;
    const float* U1 = uw1 + (size_t)l * 2 * HD * HD;
    for (int k = 0; k < HD; ++k) {
      const float w = U1[k*HD + j];
      #pragma unroll
      for (int nn = 0; nn < NPBU; ++nn) aU[nn] += hr[nn][k]*w;
    }
    for (int k = 0; k < HD; ++k) {
      const float w = U1[(HD + k)*HD + j];
      #pragma unroll
      for (int nn = 0; nn < NPBU; ++nn) aU[nn] += ar[nn][k]*w;
    }
    const float b1v = ub1[l*HD + j];
    #pragma unroll
    for (int nn = 0; nn < NPBU; ++nn) ur[nn][j] = silu_f(aU[nn] + b1v);
  }
  __syncthreads();
  // Phase 4: u2 + residual + LN
  {
    float aV[NPBU];
    #pragma unroll
    for (int nn = 0; nn < NPBU; ++nn) aV[nn] = 0.f;
    const float* U2 = uw2 + (size_t)l * HD * HD;
    for (int k = 0; k < HD; ++k) {
      const float w = U2[k*HD + j];
      #pragma unroll
      for (int nn = 0; nn < NPBU; ++nn) aV[nn] += ur[nn][k]*w;
    }
    const float b2v = ub2[l*HD + j];
    const float gv = lng[l*HD + j], bv = lnb[l*HD + j];
    float xs[NPBU];
    #pragma unroll
    for (int nn = 0; nn < NPBU; ++nn) {
      xs[nn] = hr[nn][j] + aV[nn] + b2v;
      float s = xs[nn], q = xs[nn]*xs[nn];
      #pragma unroll
      for (int o = 32; o > 0; o >>= 1) { s += __shfl_down(s, o); q += __shfl_down(q, o); }
      if ((j & 63) == 0) { sm[j >> 6][nn] = s; sq[j >> 6][nn] = q; }
    }
    __syncthreads();
    #pragma unroll
    for (int nn = 0; nn < NPBU; ++nn) {
      const float mean = (sm[0][nn] + sm[1][nn]) * (1.0f/HD);
      const float var  = (sq[0][nn] + sq[1][nn]) * (1.0f/HD) - mean*mean;
      h[(n0 + nn)*HD + j] = (xs[nn] - mean) * rsqrtf(var + 1e-5f) * gv + bv;
    }
  }
}

// ---------------- K7: pool ligand nodes + head MLP ----------------
__global__ void k_head(const float* __restrict__ h, const float* __restrict__ hw1,
                       const float* __restrict__ hb1, const float* __restrict__ hw2,
                       const float* __restrict__ hb2, float* __restrict__ out) {
  const int b = blockIdx.x, j = threadIdx.x;
  __shared__ float pool[HD], mid[HD];
  __shared__ float sm[2];
  float s = 0.f;
  #pragma unroll
  for (int i = 0; i < NLIG; ++i) s += h[(b*NNODE + i)*HD + j];
  pool[j] = s * (1.0f/NLIG);
  __syncthreads();
  float acc = hb1[j];
  for (int k = 0; k < HD; ++k) acc += pool[k] * hw1[k*HD + j];
  mid[j] = silu_f(acc);
  __syncthreads();
  float v = mid[j] * hw2[j];
  #pragma unroll
  for (int o = 32; o > 0; o >>= 1) v += __shfl_down(v, o);
  if ((j & 63) == 0) sm[j >> 6] = v;
  __syncthreads();
  if (j == 0) out[b] = sm[0] + sm[1] + hb2[0];
}

// ---------------- launcher ----------------
extern "C" void kernel_launch(void* const* d_in, const int* in_sizes, int n_in,
                              void* d_out, int out_size, void* d_ws, size_t ws_size,
                              hipStream_t stream) {
  (void)in_sizes; (void)n_in; (void)out_size; (void)ws_size;
  const float* ligc = (const float*)d_in[0];
  const float* pocc = (const float*)d_in[1];
  const float* tarr = (const float*)d_in[2];
  const float* w_in = (const float*)d_in[3];
  const float* b_in = (const float*)d_in[4];
  const float* nemb = (const float*)d_in[5];
  const float* lnig = (const float*)d_in[6];
  const float* lnib = (const float*)d_in[7];
  const float* tw1  = (const float*)d_in[8];
  const float* tb1  = (const float*)d_in[9];
  const float* tw2  = (const float*)d_in[10];
  const float* tb2  = (const float*)d_in[11];
  const float* eemb = (const float*)d_in[12];
  const float* mw1  = (const float*)d_in[13];
  const float* mb1  = (const float*)d_in[14];
  const float* mw2  = (const float*)d_in[15];
  const float* mb2  = (const float*)d_in[16];
  const float* uw1  = (const float*)d_in[17];
  const float* ub1  = (const float*)d_in[18];
  const float* uw2  = (const float*)d_in[19];
  const float* ub2  = (const float*)d_in[20];
  const float* lng  = (const float*)d_in[21];
  const float* lnb  = (const float*)d_in[22];
  const float* hw1  = (const float*)d_in[23];
  const float* hb1  = (const float*)d_in[24];
  const float* hw2  = (const float*)d_in[25];
  const float* hb2  = (const float*)d_in[26];
  float* outp = (float*)d_out;

  float* ws  = (float*)d_ws;
  float* te  = ws;                 // [16][128]
  float* h   = te  + NBATCH*HD;    // [3584][128]
  float* hs  = h   + TOTN*HD;
  float* hd  = hs  + TOTN*HD;
  float* agg = hd  + TOTN*HD;
  float* eb  = agg + TOTN*HD;      // [4][128]
  half_t* w2h   = (half_t*)(eb + 4*HD);      // [L][128][128] f16 (transposed W2)
  half_t* wrbfh = w2h + (size_t)NLAYER*HD*HD; // [L][128][32] f16 (rbf|dist weights, [j][k])

  const int SMEM_EDGES = 128*LDH*2 + 128*RADH*2 + 128*4;  // 45568
  hipFuncSetAttribute((const void*)k_edges, hipFuncAttributeMaxDynamicSharedMemorySize, SMEM_EDGES);

  k_time<<<NBATCH, HD, 0, stream>>>(tarr, tw1, tb1, tw2, tb2, te);
  k_init<<<TOTN, HD, 0, stream>>>(ligc, pocc, w_in, b_in, nemb, te, lnig, lnib, h);
  k_w2cvt<<<12, 256, 0, stream>>>(mw2, mw1, w2h, wrbfh);
  for (int l = 0; l < NLAYER; ++l) {
    k_project<<<TOTN/NPBP + 1, HD, 0, stream>>>(h, mw1, mb1, eemb, hs, hd, agg, eb, l);
    k_edges<<<NTILE, 256, SMEM_EDGES, stream>>>(ligc, pocc, hs, hd, wrbfh, mb2, w2h, eb, agg, l);
    k_update<<<TOTN/NPBU, HD, 0, stream>>>(ligc, pocc, hs, hd, mw1, mb2, mw2, eb, agg,
                                           uw1, ub1, uw2, ub2, lng, lnb, h, l);
  }
  k_head<<<NBATCH, HD, 0, stream>>>(h, hw1, hb1, hw2, hb2, outp);
}

// Round 10
// 452.035 us; speedup vs baseline: 3.2895x; 1.1241x over previous
//
#include <hip/hip_runtime.h>
#include <math.h>

// ---------------- problem constants ----------------
#define NBATCH 16
#define NLIG   32
#define NPOC   192
#define NNODE  224                 // nodes per graph
#define TOTN   (NBATCH*NNODE)      // 3584
#define HD     128
#define NLAYER 4
#define NRBF   16
#define TDIMC  64
#define EBI2   (NBATCH*NLIG*NPOC)  // 98304 type-2 edges (poc->lig)
#define NTILE  ((2*EBI2)/128)      // 1536 edge tiles per layer
#define NPBP   4                   // nodes per block in project
#define NPBU   4                   // nodes per block in update
#define GAMMA_C 14.0625f           // (15/4)^2
#define RSTEP   0.26666666666666666f // 4/15
#define TWOPI   6.283185307179586f
#define LDH    136                 // half stride for MFMA LDS m-tile (16B-aligned rows)
#define RADH   40                  // half stride for rad_h rows (16B-aligned, bank-spread)

typedef _Float16 half_t;
typedef __attribute__((ext_vector_type(8))) _Float16 half8;
typedef __attribute__((ext_vector_type(4))) _Float16 half4;
typedef __attribute__((ext_vector_type(4))) float f32x4;

__device__ __forceinline__ float silu_f(float x) { return x / (1.0f + __expf(-x)); }

// ---------------- K1: time embedding MLP  te[B][H] ----------------
__global__ void k_time(const float* __restrict__ t,
                       const float* __restrict__ w1, const float* __restrict__ b1,
                       const float* __restrict__ w2, const float* __restrict__ b2,
                       float* __restrict__ te) {
  __shared__ float emb[TDIMC];
  __shared__ float mid[HD];
  const int b = blockIdx.x, j = threadIdx.x;
  if (j < TDIMC) {
    const int half = TDIMC / 2;               // 32
    const float tv = t[b];
    const int i = j & 31;
    const float f = __expf(-logf(10000.0f) / (float)(half - 1) * (float)i);
    const float a = tv * f;
    emb[j] = (j < half) ? sinf(a) : cosf(a);
  }
  __syncthreads();
  float acc = b1[j];
  for (int k = 0; k < TDIMC; ++k) acc += emb[k] * w1[k*HD + j];
  mid[j] = silu_f(acc);
  __syncthreads();
  float acc2 = b2[j];
  for (int k = 0; k < HD; ++k) acc2 += mid[k] * w2[k*HD + j];
  te[b*HD + j] = acc2;
}

// ---------------- K2: node init + LN ----------------
__global__ void k_init(const float* __restrict__ ligc, const float* __restrict__ pocc,
                       const float* __restrict__ w_in, const float* __restrict__ b_in,
                       const float* __restrict__ nemb, const float* __restrict__ te,
                       const float* __restrict__ lng, const float* __restrict__ lnb,
                       float* __restrict__ h) {
  const int n = blockIdx.x, j = threadIdx.x;
  const int g = n / NNODE, loc = n - g*NNODE;
  const bool isl = loc < NLIG;
  float cx, cy, ang;
  if (isl) { cx = ligc[(g*NLIG + loc)*2]; cy = ligc[(g*NLIG + loc)*2 + 1];
             ang = TWOPI * (float)loc / 32.0f; }
  else { const int lp = loc - NLIG;
         cx = pocc[(g*NPOC + lp)*2]; cy = pocc[(g*NPOC + lp)*2 + 1];
         ang = TWOPI * (float)lp / 192.0f; }
  const float sa = sinf(ang), ca = cosf(ang);
  const int ty = isl ? 1 : 0;
  const float v = b_in[j] + cx*w_in[j] + cy*w_in[HD + j] + sa*w_in[2*HD + j]
                + ca*w_in[3*HD + j] + nemb[ty*HD + j] + te[g*HD + j];
  __shared__ float sm[2], sq[2];
  float s = v, q = v*v;
  #pragma unroll
  for (int o = 32; o > 0; o >>= 1) { s += __shfl_down(s, o); q += __shfl_down(q, o); }
  if ((j & 63) == 0) { sm[j >> 6] = s; sq[j >> 6] = q; }
  __syncthreads();
  const float mean = (sm[0] + sm[1]) * (1.0f/HD);
  const float var  = (sq[0] + sq[1]) * (1.0f/HD) - mean*mean;
  h[n*HD + j] = (v - mean) * rsqrtf(var + 1e-5f) * lng[j] + lnb[j];
}

// ---------------- K-CVT: W2 -> f16 [j][k]; Wrbf -> f16 [j][32]; eb (all layers) ----------------
__global__ void k_w2cvt(const float* __restrict__ mw2, const float* __restrict__ mw1,
                        const float* __restrict__ mb1, const float* __restrict__ eemb,
                        half_t* __restrict__ w2h, half_t* __restrict__ wrbfh,
                        float* __restrict__ eb) {
  const int t = threadIdx.x;
  if (blockIdx.x >= 12) {  // eb block: layer l, all 4 etypes
    const int l = blockIdx.x - 12;
    const float* W1 = mw1 + (size_t)l * 401 * HD;
    const int j = t & 127, eth = t >> 7;
    for (int et = eth; et < 4; et += 2) {
      const float* ef = eemb + ((size_t)l * 4 + et) * HD;
      float acc = mb1[l*HD + j];
      for (int k = 0; k < HD; ++k) acc += ef[k] * W1[(256 + k)*HD + j];
      eb[(l*4 + et)*HD + j] = acc;
    }
    return;
  }
  if (blockIdx.x >= 8) {   // wrbfh block: layer l; rows j, k: 0..15 rbf, 16 wdst, 17..31 zero
    const int l = blockIdx.x - 8;
    const float* W1 = mw1 + (size_t)l * 401 * HD;
    const int j = t & 127, k0 = (t >> 7) * 16;
    half_t* out = wrbfh + (size_t)l*HD*32 + (size_t)j*32 + k0;
    for (int k = k0; k < k0 + 16; ++k) {
      float v = 0.f;
      if (k < 16) v = W1[(384 + k)*HD + j];
      else if (k == 16) v = W1[400*HD + j];
      out[k - k0] = (half_t)v;
    }
    return;
  }
  __shared__ float ft[64][129];
  const int l = blockIdx.x >> 1, k0 = (blockIdx.x & 1) * 64;
  const float* W2 = mw2 + (size_t)l*HD*HD;
  for (int i = 0; i < 32; ++i) {
    const int idx = t + i*256;           // 8192 = 64k x 128j
    const int k = idx >> 7, j = idx & 127;
    ft[k][j] = W2[(k0 + k)*HD + j];
  }
  __syncthreads();
  half_t* out = w2h + (size_t)l*HD*HD;
  for (int i = 0; i < 32; ++i) {
    const int idx = t + i*256;           // 8192 = 128j x 64k
    const int j = idx >> 6, k = idx & 63;
    out[j*HD + k0 + k] = (half_t)ft[k][j];
  }
}

// ---------------- K3: layer-0 projections hs = h@W1s, hd = h@W1d; zero agg ----------------
__global__ void k_project(const float* __restrict__ h, const float* __restrict__ mw1,
                          float* __restrict__ hs, float* __restrict__ hd,
                          float* __restrict__ agg) {
  const int j = threadIdx.x;
  const float* W1 = mw1;   // layer 0
  __shared__ float hr[NPBP][HD];
  const int n0 = blockIdx.x * NPBP;
  #pragma unroll
  for (int nn = 0; nn < NPBP; ++nn) hr[nn][j] = h[(n0 + nn)*HD + j];
  __syncthreads();
  float as[NPBP], ad[NPBP];
  #pragma unroll
  for (int nn = 0; nn < NPBP; ++nn) { as[nn] = 0.f; ad[nn] = 0.f; }
  for (int k = 0; k < HD; ++k) {
    const float ws = W1[k*HD + j];
    const float wd = W1[(128 + k)*HD + j];
    #pragma unroll
    for (int nn = 0; nn < NPBP; ++nn) { as[nn] += hr[nn][k]*ws; ad[nn] += hr[nn][k]*wd; }
  }
  #pragma unroll
  for (int nn = 0; nn < NPBP; ++nn) {
    hs[(n0 + nn)*HD + j]  = as[nn];
    hd[(n0 + nn)*HD + j]  = ad[nn];
    agg[(n0 + nn)*HD + j] = 0.f;
  }
}

// ---------------- K5: bipartite edge messages — dual-MFMA, fused epilogue ----------------
// Phase A: rad_h[e][32] f16. Phase B: rbf-dot MFMA (A=Wrbf rows=j, B=rad cols=e)
// + in-register epilogue (hs[src]+hd[dst]+eb, silu) -> single m_t write.
// Phase C: W2 MFMA + full-wave reduce + one atomic per (dst,col).
__global__ __launch_bounds__(256, 3)
void k_edges(const float* __restrict__ ligc, const float* __restrict__ pocc,
             const float* __restrict__ hs, const float* __restrict__ hd,
             const half_t* __restrict__ wrbfh, const float* __restrict__ mb2,
             const half_t* __restrict__ w2h, const float* __restrict__ eb,
             float* __restrict__ agg, int l) {
  extern __shared__ char lds_raw[];
  half_t* m_t   = (half_t*)lds_raw;                  // [128][LDH]
  half_t* rad_h = m_t + 128*LDH;                     // [128][RADH] (k 0..31 valid)
  float*  b2l   = (float*)(rad_h + 128*RADH);        // [128]

  const int tid = threadIdx.x;
  const int bid = blockIdx.x;
  const int et  = (bid < NTILE/2) ? 2 : 3;

  // Phase A: per-edge geometry -> rad_h[] (one thread per edge)
  if (tid < 128) {
    b2l[tid] = mb2[l*HD + tid];
    const int e = tid;
    int g, sl, dl;
    if (et == 2) {
      const int idx = bid*128 + e;
      g = idx / 6144; const int r0 = idx - g*6144;
      const int i = r0 / 192; const int p = r0 - i*192;
      sl = NLIG + p; dl = i;
    } else {
      const int idx = bid*128 + e - EBI2;
      g = idx / 6144; const int r0 = idx - g*6144;
      const int p = r0 >> 5; const int i = r0 & 31;
      sl = i; dl = NLIG + p;
    }
    float sx, sy, dx, dy;
    if (sl < NLIG) { sx = ligc[(g*NLIG + sl)*2]; sy = ligc[(g*NLIG + sl)*2 + 1]; }
    else { const int lp = sl - NLIG; sx = pocc[(g*NPOC + lp)*2]; sy = pocc[(g*NPOC + lp)*2 + 1]; }
    if (dl < NLIG) { dx = ligc[(g*NLIG + dl)*2]; dy = ligc[(g*NLIG + dl)*2 + 1]; }
    else { const int lp = dl - NLIG; dx = pocc[(g*NPOC + lp)*2]; dy = pocc[(g*NPOC + lp)*2 + 1]; }
    const float rx = sx - dx, ry = sy - dy;
    const float d = sqrtf(rx*rx + ry*ry);
    half_t* rp = rad_h + e*RADH;
    #pragma unroll
    for (int rr = 0; rr < NRBF; ++rr) {
      const float u = d - RSTEP * (float)rr;
      rp[rr] = (half_t)__expf(-GAMMA_C * u * u);
    }
    rp[16] = (half_t)d;
    #pragma unroll
    for (int k = 17; k < 32; ++k) rp[k] = (half_t)0.f;
  }
  __syncthreads();

  // Phase B: rbf-dot MFMA + fused epilogue -> m_t (one write per element)
  {
    const int lane = tid & 63;
    const int q = lane >> 4, c15 = lane & 15;
    const int ebase = (tid >> 6) * 32;
    // per-lane src rows for the two edge half-blocks; wave-uniform dst
    int srcA, srcB, dst;
    if (et == 2) {
      const int idxA = bid*128 + ebase + c15;
      const int g = idxA / 6144; const int r0 = idxA - g*6144;
      const int i = r0 / 192, p = r0 - i*192;
      dst  = g*NNODE + i;
      srcA = g*NNODE + NLIG + p;
      srcB = srcA + 16;                          // same 192-run (32-span)
    } else {
      const int idxA = bid*128 + ebase + c15 - EBI2;
      const int g = idxA / 6144; const int r0 = idxA - g*6144;
      const int p = r0 >> 5, i = r0 & 31;
      dst  = g*NNODE + NLIG + p;
      srcA = g*NNODE + i;
      srcB = g*NNODE + ((i + 16) & 31);          // wraps within the 32-run
    }
    const float* hdrow = hd + (size_t)dst*HD;
    const float* ebrow = eb + (size_t)(l*4 + et)*HD;
    const float* hsA   = hs + (size_t)srcA*HD;
    const float* hsB   = hs + (size_t)srcB*HD;
    const half_t* WR = wrbfh + (size_t)l*HD*32;
    half8 af[8];
    #pragma unroll
    for (int jb = 0; jb < 8; ++jb)
      af[jb] = *(const half8*)&WR[(size_t)(jb*16 + c15)*32 + 8*q];
    const half8 bfA = *(const half8*)&rad_h[(ebase + c15)*RADH + 8*q];
    const half8 bfB = *(const half8*)&rad_h[(ebase + 16 + c15)*RADH + 8*q];
    const int eA = ebase + c15, eB = ebase + 16 + c15;
    #pragma unroll
    for (int jb = 0; jb < 8; ++jb) {
      const int j0 = jb*16 + q*4;
      f32x4 hde = *(const f32x4*)&hdrow[j0];
      const f32x4 ebv = *(const f32x4*)&ebrow[j0];
      #pragma unroll
      for (int r = 0; r < 4; ++r) hde[r] += ebv[r];
      f32x4 zero = (f32x4){0.f,0.f,0.f,0.f};
      f32x4 aA = __builtin_amdgcn_mfma_f32_16x16x32_f16(af[jb], bfA, zero, 0, 0, 0);
      f32x4 aB = __builtin_amdgcn_mfma_f32_16x16x32_f16(af[jb], bfB, zero, 0, 0, 0);
      const f32x4 ha = *(const f32x4*)&hsA[j0];
      const f32x4 hb = *(const f32x4*)&hsB[j0];
      half4 hvA, hvB;
      #pragma unroll
      for (int r = 0; r < 4; ++r) {
        hvA[r] = (half_t)silu_f(aA[r] + ha[r] + hde[r]);
        hvB[r] = (half_t)silu_f(aB[r] + hb[r] + hde[r]);
      }
      *(half4*)&m_t[(size_t)eA*LDH + j0] = hvA;
      *(half4*)&m_t[(size_t)eB*LDH + j0] = hvB;
    }
  }
  __syncthreads();

  // Phase C: MFMA [128e x 128k] @ [128k x 128j]; silu; full-wave reduce; one atomic set
  {
    const int wv = tid >> 6, lane = tid & 63;
    const int q = lane >> 4, c15 = lane & 15;
    const int ebase = wv*32;
    int dst;
    if (et == 2) {
      const int idx = bid*128 + ebase;
      const int g = idx / 6144; const int r0 = idx - g*6144;
      dst = g*NNODE + r0/192;
    } else {
      const int idx = bid*128 + ebase - EBI2;
      const int g = idx / 6144; const int r0 = idx - g*6144;
      dst = g*NNODE + NLIG + (r0 >> 5);
    }
    const half_t* W2H = w2h + (size_t)l*HD*HD;
    f32x4 acc[2][8];
    #pragma unroll
    for (int ii = 0; ii < 2; ++ii)
      #pragma unroll
      for (int jj = 0; jj < 8; ++jj) acc[ii][jj] = (f32x4){0.f,0.f,0.f,0.f};
    for (int k0 = 0; k0 < HD; k0 += 32) {
      half8 af[2], bf[8];
      #pragma unroll
      for (int ii = 0; ii < 2; ++ii)
        af[ii] = *(const half8*)&m_t[(ebase + ii*16 + c15)*LDH + k0 + 8*q];
      #pragma unroll
      for (int jj = 0; jj < 8; ++jj)
        bf[jj] = *(const half8*)&W2H[(size_t)(jj*16 + c15)*HD + k0 + 8*q];
      #pragma unroll
      for (int ii = 0; ii < 2; ++ii)
        #pragma unroll
        for (int jj = 0; jj < 8; ++jj)
          acc[ii][jj] = __builtin_amdgcn_mfma_f32_16x16x32_f16(af[ii], bf[jj], acc[ii][jj], 0, 0, 0);
    }
    #pragma unroll
    for (int jj = 0; jj < 8; ++jj) {
      const int col = jj*16 + c15;
      const float bb = b2l[col];
      float s = 0.f;
      #pragma unroll
      for (int ii = 0; ii < 2; ++ii) {
        s += silu_f(acc[ii][jj][0] + bb) + silu_f(acc[ii][jj][1] + bb)
           + silu_f(acc[ii][jj][2] + bb) + silu_f(acc[ii][jj][3] + bb);
      }
      s += __shfl_xor(s, 16);
      s += __shfl_xor(s, 32);
      if (q == 0) atomicAdd(&agg[(size_t)dst*HD + col], s);
    }
  }
}

// ---------------- K6: cycle edges + mean + update MLP + LN + next-layer projections ----------------
// 256 threads: hf = tid>>7 splits independent work (edge A/B, W2-A/W2-B, U1 halves,
// U2 K-halves, hs/hd). Writes next-layer hs/hd (ping-pong buffers) when l<3.
__global__ __launch_bounds__(256, 4)
void k_update(const float* __restrict__ ligc, const float* __restrict__ pocc,
              const float* __restrict__ hs, const float* __restrict__ hd,
              const float* __restrict__ mw1, const float* __restrict__ mb2,
              const float* __restrict__ mw2, const float* __restrict__ eb,
              float* __restrict__ agg,
              const float* __restrict__ uw1, const float* __restrict__ ub1,
              const float* __restrict__ uw2, const float* __restrict__ ub2,
              const float* __restrict__ lng, const float* __restrict__ lnb,
              float* __restrict__ h, float* __restrict__ hsn, float* __restrict__ hdn,
              int l) {
  const int tid = threadIdx.x;
  const int j = tid & 127, hf = tid >> 7;
  const int n0 = blockIdx.x * NPBU;
  __shared__ float wrbf[NRBF*HD];
  __shared__ float wdst[HD], ebs[2*HD], b2s[HD];
  __shared__ float mAB[2][NPBU][HD];
  __shared__ float hr[NPBU][HD], ar[NPBU][HD], ur[NPBU][HD], ag[NPBU][HD], hnew[NPBU][HD];
  __shared__ float pP[2][NPBU][HD];
  __shared__ float radS[NPBU][2][NRBF];
  __shared__ float distS[NPBU][2];
  __shared__ float sm[2][NPBU], sq[2][NPBU];
  const float* W1 = mw1 + (size_t)l * 401 * HD;
  const float* W2 = mw2 + (size_t)l * HD * HD;
  for (int idx = tid; idx < NRBF*HD; idx += 256) wrbf[idx] = W1[384*HD + idx];
  if (hf == 0) {
    wdst[j] = W1[400*HD + j];
    b2s[j]  = mb2[l*HD + j];
  } else {
    ebs[j]      = eb[(l*4 + 0)*HD + j];
    ebs[HD + j] = eb[(l*4 + 1)*HD + j];
  }
  if (tid < 128) { // geometry: (nn = tid>>5, rr = tid&31), rr<16 active
    const int nn = tid >> 5, rr = tid & 31;
    if (rr < 16) {
      const int n = n0 + nn;
      const int g = n / NNODE, loc = n - g*NNODE;
      const bool isl = loc < NLIG;
      float nx, ny;
      if (isl) { nx = ligc[(g*NLIG + loc)*2]; ny = ligc[(g*NLIG + loc)*2 + 1]; }
      else { const int lp = loc - NLIG; nx = pocc[(g*NPOC + lp)*2]; ny = pocc[(g*NPOC + lp)*2 + 1]; }
      #pragma unroll
      for (int ab = 0; ab < 2; ++ab) {
        int sl;
        if (isl) sl = (ab == 0) ? ((loc + NLIG - 1) & 31) : ((loc + 1) & 31);
        else { const int lp = loc - NLIG;
               const int sp = (ab == 0) ? (lp + NPOC - 1) % NPOC : (lp + 1) % NPOC;
               sl = NLIG + sp; }
        float sx, sy;
        if (sl < NLIG) { sx = ligc[(g*NLIG + sl)*2]; sy = ligc[(g*NLIG + sl)*2 + 1]; }
        else { const int lp = sl - NLIG; sx = pocc[(g*NPOC + lp)*2]; sy = pocc[(g*NPOC + lp)*2 + 1]; }
        const float rx = sx - nx, ry = sy - ny;
        const float d = sqrtf(rx*rx + ry*ry);
        const float u = d - RSTEP * (float)rr;
        radS[nn][ab][rr] = __expf(-GAMMA_C * u * u);
        if (rr == 0) distS[nn][ab] = d;
      }
    }
  }
  __syncthreads();
  // Phase 1: hf0 -> edge A (+hr stage), hf1 -> edge B (+agg stage)
  #pragma unroll
  for (int nn = 0; nn < NPBU; ++nn) {
    const int n = n0 + nn;
    const int g = n / NNODE, loc = n - g*NNODE;
    const bool isl = loc < NLIG;
    int sl, etc_;
    if (isl) { sl = (hf == 0) ? ((loc + NLIG - 1) & 31) : ((loc + 1) & 31); etc_ = 0; }
    else { const int lp = loc - NLIG;
           sl = NLIG + ((hf == 0) ? (lp + NPOC - 1) % NPOC : (lp + 1) % NPOC); etc_ = 1; }
    const int sn = g*NNODE + sl;
    const float base = hd[(size_t)n*HD + j] + ebs[etc_*HD + j];
    float p = hs[(size_t)sn*HD + j] + base + distS[nn][hf]*wdst[j];
    #pragma unroll
    for (int rr = 0; rr < NRBF; ++rr) p += radS[nn][hf][rr] * wrbf[rr*HD + j];
    mAB[hf][nn][j] = silu_f(p);
    if (hf == 0) hr[nn][j] = h[(size_t)n*HD + j];
    else         ag[nn][j] = agg[(size_t)n*HD + j];
  }
  __syncthreads();
  // Phase 2: hf matvec of its own mAB half over full K
  {
    float a[NPBU];
    #pragma unroll
    for (int nn = 0; nn < NPBU; ++nn) a[nn] = 0.f;
    for (int k = 0; k < HD; ++k) {
      const float w = W2[k*HD + j];
      #pragma unroll
      for (int nn = 0; nn < NPBU; ++nn) a[nn] += mAB[hf][nn][k]*w;
    }
    #pragma unroll
    for (int nn = 0; nn < NPBU; ++nn) pP[hf][nn][j] = a[nn];
  }
  __syncthreads();
  { // combine: nn split by hf
    const float b = b2s[j];
    for (int nn = hf*2; nn < hf*2 + 2; ++nn) {
      const int loc = (n0 + nn) % NNODE;
      const float inv_deg = (loc < NLIG) ? (1.0f/194.0f) : (1.0f/34.0f);
      ar[nn][j] = (ag[nn][j] + silu_f(pP[0][nn][j] + b) + silu_f(pP[1][nn][j] + b)) * inv_deg;
    }
  }
  __syncthreads();
  // Phase 3: u1 halves — hf0: h-part, hf1: ar-part
  {
    const float* U1 = uw1 + (size_t)l*2*HD*HD + (size_t)hf*HD*HD;
    const float (*src)[HD] = (hf == 0) ? hr : ar;
    float a[NPBU];
    #pragma unroll
    for (int nn = 0; nn < NPBU; ++nn) a[nn] = 0.f;
    for (int k = 0; k < HD; ++k) {
      const float w = U1[k*HD + j];
      #pragma unroll
      for (int nn = 0; nn < NPBU; ++nn) a[nn] += src[nn][k]*w;
    }
    #pragma unroll
    for (int nn = 0; nn < NPBU; ++nn) pP[hf][nn][j] = a[nn];
  }
  __syncthreads();
  {
    const float b1v = ub1[l*HD + j];
    for (int nn = hf*2; nn < hf*2 + 2; ++nn)
      ur[nn][j] = silu_f(pP[0][nn][j] + pP[1][nn][j] + b1v);
  }
  __syncthreads();
  // Phase 4: u2, K split 64/64
  {
    const float* U2 = uw2 + (size_t)l*HD*HD;
    float a[NPBU];
    #pragma unroll
    for (int nn = 0; nn < NPBU; ++nn) a[nn] = 0.f;
    const int kb = hf*64;
    for (int k = kb; k < kb + 64; ++k) {
      const float w = U2[k*HD + j];
      #pragma unroll
      for (int nn = 0; nn < NPBU; ++nn) a[nn] += ur[nn][k]*w;
    }
    #pragma unroll
    for (int nn = 0; nn < NPBU; ++nn) pP[hf][nn][j] = a[nn];
  }
  __syncthreads();
  // Residual + LN (stats from hf0 waves)
  {
    const float b2v = ub2[l*HD + j];
    float xs[NPBU];
    #pragma unroll
    for (int nn = 0; nn < NPBU; ++nn) {
      xs[nn] = hr[nn][j] + pP[0][nn][j] + pP[1][nn][j] + b2v;
      float s = xs[nn], qq = xs[nn]*xs[nn];
      #pragma unroll
      for (int o = 32; o > 0; o >>= 1) { s += __shfl_down(s, o); qq += __shfl_down(qq, o); }
      if (((j & 63) == 0) && hf == 0) { sm[j >> 6][nn] = s; sq[j >> 6][nn] = qq; }
    }
    __syncthreads();
    if (hf == 0) {
      const float gv = lng[l*HD + j], bv = lnb[l*HD + j];
      #pragma unroll
      for (int nn = 0; nn < NPBU; ++nn) {
        const float mean = (sm[0][nn] + sm[1][nn]) * (1.0f/HD);
        const float var  = (sq[0][nn] + sq[1][nn]) * (1.0f/HD) - mean*mean;
        const float v = (xs[nn] - mean) * rsqrtf(var + 1e-5f) * gv + bv;
        h[(size_t)(n0 + nn)*HD + j] = v;
        hnew[nn][j] = v;
      }
    }
  }
  __syncthreads();
  // Phase 5 (l<3): next-layer projections hs/hd for these nodes; reset agg
  if (l < 3) {
    const float* W1n = mw1 + (size_t)(l+1)*401*HD + (size_t)(hf ? 128 : 0)*HD;
    float a[NPBU];
    #pragma unroll
    for (int nn = 0; nn < NPBU; ++nn) a[nn] = 0.f;
    for (int k = 0; k < HD; ++k) {
      const float w = W1n[k*HD + j];
      #pragma unroll
      for (int nn = 0; nn < NPBU; ++nn) a[nn] += hnew[nn][k]*w;
    }
    float* outp = (hf == 0) ? hsn : hdn;
    #pragma unroll
    for (int nn = 0; nn < NPBU; ++nn) outp[(size_t)(n0 + nn)*HD + j] = a[nn];
    if (hf == 0) {
      #pragma unroll
      for (int nn = 0; nn < NPBU; ++nn) agg[(size_t)(n0 + nn)*HD + j] = 0.f;
    }
  }
}

// ---------------- K7: pool ligand nodes + head MLP ----------------
__global__ void k_head(const float* __restrict__ h, const float* __restrict__ hw1,
                       const float* __restrict__ hb1, const float* __restrict__ hw2,
                       const float* __restrict__ hb2, float* __restrict__ out) {
  const int b = blockIdx.x, j = threadIdx.x;
  __shared__ float pool[HD], mid[HD];
  __shared__ float sm[2];
  float s = 0.f;
  #pragma unroll
  for (int i = 0; i < NLIG; ++i) s += h[(b*NNODE + i)*HD + j];
  pool[j] = s * (1.0f/NLIG);
  __syncthreads();
  float acc = hb1[j];
  for (int k = 0; k < HD; ++k) acc += pool[k] * hw1[k*HD + j];
  mid[j] = silu_f(acc);
  __syncthreads();
  float v = mid[j] * hw2[j];
  #pragma unroll
  for (int o = 32; o > 0; o >>= 1) v += __shfl_down(v, o);
  if ((j & 63) == 0) sm[j >> 6] = v;
  __syncthreads();
  if (j == 0) out[b] = sm[0] + sm[1] + hb2[0];
}

// ---------------- launcher ----------------
extern "C" void kernel_launch(void* const* d_in, const int* in_sizes, int n_in,
                              void* d_out, int out_size, void* d_ws, size_t ws_size,
                              hipStream_t stream) {
  (void)in_sizes; (void)n_in; (void)out_size; (void)ws_size;
  const float* ligc = (const float*)d_in[0];
  const float* pocc = (const float*)d_in[1];
  const float* tarr = (const float*)d_in[2];
  const float* w_in = (const float*)d_in[3];
  const float* b_in = (const float*)d_in[4];
  const float* nemb = (const float*)d_in[5];
  const float* lnig = (const float*)d_in[6];
  const float* lnib = (const float*)d_in[7];
  const float* tw1  = (const float*)d_in[8];
  const float* tb1  = (const float*)d_in[9];
  const float* tw2  = (const float*)d_in[10];
  const float* tb2  = (const float*)d_in[11];
  const float* eemb = (const float*)d_in[12];
  const float* mw1  = (const float*)d_in[13];
  const float* mb1  = (const float*)d_in[14];
  const float* mw2  = (const float*)d_in[15];
  const float* mb2  = (const float*)d_in[16];
  const float* uw1  = (const float*)d_in[17];
  const float* ub1  = (const float*)d_in[18];
  const float* uw2  = (const float*)d_in[19];
  const float* ub2  = (const float*)d_in[20];
  const float* lng  = (const float*)d_in[21];
  const float* lnb  = (const float*)d_in[22];
  const float* hw1  = (const float*)d_in[23];
  const float* hb1  = (const float*)d_in[24];
  const float* hw2  = (const float*)d_in[25];
  const float* hb2  = (const float*)d_in[26];
  float* outp = (float*)d_out;

  float* ws  = (float*)d_ws;
  float* te  = ws;                    // [16][128]
  float* h   = te  + NBATCH*HD;       // [3584][128]
  float* hs0 = h   + TOTN*HD;
  float* hd0 = hs0 + TOTN*HD;
  float* hs1 = hd0 + TOTN*HD;
  float* hd1 = hs1 + TOTN*HD;
  float* agg = hd1 + TOTN*HD;
  float* eb  = agg + TOTN*HD;         // [L][4][128]
  half_t* w2h   = (half_t*)(eb + 16*HD);       // [L][128][128] f16 (transposed W2)
  half_t* wrbfh = w2h + (size_t)NLAYER*HD*HD;  // [L][128][32] f16 (rbf|dist weights)

  float* hsb[2] = {hs0, hs1};
  float* hdb[2] = {hd0, hd1};

  const int SMEM_EDGES = 128*LDH*2 + 128*RADH*2 + 128*4;  // 45568
  hipFuncSetAttribute((const void*)k_edges, hipFuncAttributeMaxDynamicSharedMemorySize, SMEM_EDGES);

  k_time<<<NBATCH, HD, 0, stream>>>(tarr, tw1, tb1, tw2, tb2, te);
  k_init<<<TOTN, HD, 0, stream>>>(ligc, pocc, w_in, b_in, nemb, te, lnig, lnib, h);
  k_w2cvt<<<16, 256, 0, stream>>>(mw2, mw1, mb1, eemb, w2h, wrbfh, eb);
  k_project<<<TOTN/NPBP, HD, 0, stream>>>(h, mw1, hs0, hd0, agg);
  for (int l = 0; l < NLAYER; ++l) {
    const int cur = l & 1, nxt = cur ^ 1;
    k_edges<<<NTILE, 256, SMEM_EDGES, stream>>>(ligc, pocc, hsb[cur], hdb[cur],
                                                wrbfh, mb2, w2h, eb, agg, l);
    k_update<<<TOTN/NPBU, 256, 0, stream>>>(ligc, pocc, hsb[cur], hdb[cur], mw1, mb2, mw2,
                                            eb, agg, uw1, ub1, uw2, ub2, lng, lnb,
                                            h, hsb[nxt], hdb[nxt], l);
  }
  k_head<<<NBATCH, HD, 0, stream>>>(h, hw1, hb1, hw2, hb2, outp);
}